// Round 10
// baseline (180.059 us; speedup 1.0000x reference)
//
#include <hip/hip_runtime.h>
#include <hip/hip_bf16.h>
#include <hip/hip_fp16.h>

// Problem constants (from reference)
#define NN     16384   // nodes
#define HD     64      // hidden dim
#define BG     32      // graphs
#define NPG    512     // nodes per graph
#define NHEADS 8
#define DH     8
#define DEGMAX 40      // ELL width; deg ~ Poisson(16), P(>40) ~ 3e-8/node

// R30 MFMA attn LDS geometry (f16):
//   Qs[512][12], Ks[256][12]: row stride 12 f16 = 24B -> b64 fragment reads
//   8B-aligned; bank stride 6 -> only 2-way aliasing (free, m136).
//   Vt[8][264]: V transposed; row stride 528B -> the 8 dh-rows hit banks
//   {0,4,8,...,28}; b64 frag reads conflict-free; lanes 8-31 broadcast.
#define QS_STR 12
#define KS_STR 12
#define VT_STR 264

typedef __hip_bfloat16 bf16;
typedef _Float16 v4h __attribute__((ext_vector_type(4)));
typedef float v16f __attribute__((ext_vector_type(16)));

#if defined(__has_builtin)
#if __has_builtin(__builtin_amdgcn_exp2f)
#define EXP2F(x) __builtin_amdgcn_exp2f(x)
#else
#define EXP2F(x) exp2f(x)
#endif
#if __has_builtin(__builtin_amdgcn_fdot2)
#define HAS_FDOT2 1
#endif
#else
#define EXP2F(x) exp2f(x)
#endif

#ifdef HAS_FDOT2
typedef _Float16 hvec2 __attribute__((ext_vector_type(2)));
#endif

// dot2 on two packed-f16 u32 words, f32 accumulate (fallback: plain f32).
__device__ __forceinline__ float fdot2u(unsigned a, unsigned b, float c) {
#ifdef HAS_FDOT2
  union { unsigned u; hvec2 v; } x, y;
  x.u = a; y.u = b;
  return __builtin_amdgcn_fdot2(x.v, y.v, c, false);
#else
  union { unsigned u; __half2 h; } x, y;
  x.u = a; y.u = b;
  return fmaf(__low2float(x.h), __low2float(y.h),
              fmaf(__high2float(x.h), __high2float(y.h), c));
#endif
}

__device__ __forceinline__ float b2f(bf16 v) { return __bfloat162float(v); }

// Flag-steered input load: bf=1 -> buffer is bf16, bf=0 -> fp32.
__device__ __forceinline__ float ldf(const void* p, int i, int bf) {
  return bf ? __bfloat162float(((const bf16*)p)[i]) : ((const float*)p)[i];
}

__device__ __forceinline__ float wave_sum(float v) {
#pragma unroll
  for (int off = 32; off > 0; off >>= 1) v += __shfl_xor(v, off);
  return v;
}

__device__ __forceinline__ void unpack8(uint4 u, float* f) {
  f[0] = __uint_as_float(u.x << 16); f[1] = __uint_as_float(u.x & 0xffff0000u);
  f[2] = __uint_as_float(u.y << 16); f[3] = __uint_as_float(u.y & 0xffff0000u);
  f[4] = __uint_as_float(u.z << 16); f[5] = __uint_as_float(u.z & 0xffff0000u);
  f[6] = __uint_as_float(u.w << 16); f[7] = __uint_as_float(u.w & 0xffff0000u);
}

__device__ __forceinline__ unsigned short bfbits(float f) {
  bf16 b = __float2bfloat16(f);
  return *(unsigned short*)&b;
}

__device__ __forceinline__ unsigned packh2(float a, float b) {
  union { unsigned u; __half2 h; } z;
  z.h = __floats2half2_rn(a, b);
  return z.u;
}

// Per-block dtype detection (bf16 vs fp32 inputs) — only k_build pays this
// (256 samples; bf16 scores ~256, fp32 ~51 — wide margin); publishes flag.
__device__ __forceinline__ int detect_bf(const unsigned short* xr, int tid, int nt) {
  __shared__ int s_cnt;
  if (tid == 0) s_cnt = 0;
  __syncthreads();
  int sane = 0;
  for (int i = tid; i < 256; i += nt) {
    int e = (xr[2 * i] >> 7) & 0xFF;
    sane += (e >= 100 && e <= 150) ? 1 : 0;
  }
  if (sane) atomicAdd(&s_cnt, sane);
  __syncthreads();
  return s_cnt > 180;
}

// Kernel 1: h = x @ w_gat (bf16 out); as_/ad_ logit halves; + fused ELL
// scatter; + publish dtype flag. 16 nodes/block (champion config —
// 32/block regressed in R20: doubles the edge-scatter trip count).
__global__ __launch_bounds__(256) void k_build(
    const void* __restrict__ x, const void* __restrict__ w,
    const void* __restrict__ asrc, const void* __restrict__ adst,
    const int* __restrict__ esrc, const int* __restrict__ edst, int E,
    int* __restrict__ cur, int* __restrict__ ell,
    bf16* __restrict__ h, float* __restrict__ as_, float* __restrict__ ad_,
    int* __restrict__ flagp)
{
  const int tid = threadIdx.x, lane = tid & 63, wid = tid >> 6;
  const int bf = detect_bf((const unsigned short*)x, tid, 256);
  if (tid == 0 && blockIdx.x == 0) *flagp = bf;
  __shared__ float wl[HD * HD];
  __shared__ float xr[4][HD];
  {
    for (int e = blockIdx.x * 256 + tid; e < E; e += gridDim.x * 256) {
      int d = edst[e];
      int k = atomicAdd(&cur[d], 1);
      if (k < DEGMAX) ell[d * DEGMAX + k] = esrc[e];
    }
  }
  for (int i = tid; i < HD * HD; i += 256) wl[i] = ldf(w, i, bf);
  const float av = ldf(asrc, lane, bf), dv_ = ldf(adst, lane, bf);
  __syncthreads();
#pragma unroll
  for (int r = 0; r < 4; ++r) {
    const int node = blockIdx.x * 16 + r * 4 + wid;
    xr[wid][lane] = ldf(x, node * HD + lane, bf);   // wave-local slot
    float hj = 0.f;
#pragma unroll
    for (int i = 0; i < HD; ++i) hj = fmaf(xr[wid][i], wl[i * HD + lane], hj);
    float pa = wave_sum(hj * av);
    float pd = wave_sum(hj * dv_);
    h[node * HD + lane] = __float2bfloat16(hj);
    if (lane == 0) { as_[node] = pa; ad_[node] = pd; }
  }
}

// Kernel 2: wave-per-node GAT gather (ELL) + bias + relu + residual + LN1 -> x1
// R31: x1 now stored as f16 (finer mantissa than bf16; LN output bounded)
// so k_attn13 can dot2 it directly. Blocks 0-3 additionally pre-pack
// [Wq|Wk|Wv] into f16-pair words (wpk) and block 4 packs biases (bpk) —
// stream-ordered before k_attn13, which then reads W via wave-UNIFORM
// loads (scalar path) instead of 1024 LDS broadcast reads per thread.
__global__ __launch_bounds__(256) void k_gather(
    const void* __restrict__ x, const int* __restrict__ cur,
    const int* __restrict__ ell, const float* __restrict__ as_,
    const float* __restrict__ ad_, const bf16* __restrict__ h,
    const void* __restrict__ bg, const void* __restrict__ g1,
    const void* __restrict__ b1,
    const void* __restrict__ wq, const void* __restrict__ bq,
    const void* __restrict__ wk, const void* __restrict__ bk,
    const void* __restrict__ wv, const void* __restrict__ bv,
    const int* __restrict__ dflag,
    unsigned* __restrict__ wpk, float* __restrict__ bpk,
    __half* __restrict__ x1)
{
  const int tid = threadIdx.x, lane = tid & 63, wid = tid >> 6;
  const int bf = *dflag;
  // ---- QKV weight/bias pre-pack for k_attn13 (blocks 0-4 only) ----
  if (blockIdx.x < 4) {
    for (int idx = blockIdx.x * 256 + tid; idx < 3 * 32 * 64; idx += 1024) {
      int m = idx >> 11;            // 0..2 (2048 words per matrix)
      int r = idx & 2047;
      int kp = r >> 6, col = r & 63;
      const void* ws = (m == 0) ? wq : (m == 1) ? wk : wv;
      wpk[idx] = packh2(ldf(ws, (2 * kp) * HD + col, bf),
                        ldf(ws, (2 * kp + 1) * HD + col, bf));
    }
  } else if (blockIdx.x == 4 && tid < 192) {
    int m = tid >> 6, col = tid & 63;
    const void* bs = (m == 0) ? bq : (m == 1) ? bk : bv;
    bpk[tid] = ldf(bs, col, bf);
  }
  const int n = blockIdx.x * 4 + wid;
  const float adn = ad_[n];
  float e0 = as_[n] + adn;
  e0 = e0 > 0.f ? e0 : 0.2f * e0;
  float den = __expf(fminf(e0, 30.f));
  float num = den * b2f(h[n * HD + lane]);
  const int deg = min(cur[n], DEGMAX);
  const int* row = ell + n * DEGMAX;
  int i = 0;
  for (; i + 8 <= deg; i += 8) {
    int s[8];
#pragma unroll
    for (int k = 0; k < 8; ++k) s[k] = row[i + k];
    float a[8], hh[8];
#pragma unroll
    for (int k = 0; k < 8; ++k) a[k] = as_[s[k]];
#pragma unroll
    for (int k = 0; k < 8; ++k) hh[k] = b2f(h[s[k] * HD + lane]);
#pragma unroll
    for (int k = 0; k < 8; ++k) {
      float e = a[k] + adn;
      e = e > 0.f ? e : 0.2f * e;
      float p = __expf(fminf(e, 30.f));
      den += p;
      num = fmaf(p, hh[k], num);
    }
  }
  for (; i + 4 <= deg; i += 4) {
    int s0 = row[i], s1 = row[i + 1], s2 = row[i + 2], s3 = row[i + 3];
    float a0 = as_[s0], a1 = as_[s1], a2 = as_[s2], a3 = as_[s3];
    float h0 = b2f(h[s0 * HD + lane]), h1 = b2f(h[s1 * HD + lane]);
    float h2 = b2f(h[s2 * HD + lane]), h3 = b2f(h[s3 * HD + lane]);
    float e_0 = a0 + adn; e_0 = e_0 > 0.f ? e_0 : 0.2f * e_0;
    float e_1 = a1 + adn; e_1 = e_1 > 0.f ? e_1 : 0.2f * e_1;
    float e_2 = a2 + adn; e_2 = e_2 > 0.f ? e_2 : 0.2f * e_2;
    float e_3 = a3 + adn; e_3 = e_3 > 0.f ? e_3 : 0.2f * e_3;
    float p0 = __expf(fminf(e_0, 30.f)), p1 = __expf(fminf(e_1, 30.f));
    float p2 = __expf(fminf(e_2, 30.f)), p3 = __expf(fminf(e_3, 30.f));
    den += p0 + p1 + p2 + p3;
    num = fmaf(p0, h0, num); num = fmaf(p1, h1, num);
    num = fmaf(p2, h2, num); num = fmaf(p3, h3, num);
  }
  for (; i < deg; ++i) {
    int s = row[i];
    float e = as_[s] + adn;
    e = e > 0.f ? e : 0.2f * e;
    float p = __expf(fminf(e, 30.f));
    den += p;
    num = fmaf(p, b2f(h[s * HD + lane]), num);
  }
  float v = num / (den + 1e-16f) + ldf(bg, lane, bf);
  v = fmaxf(v, 0.f) + ldf(x, n * HD + lane, bf);
  float mu = wave_sum(v) * (1.f / 64.f);
  float dv = v - mu;
  float var = wave_sum(dv * dv) * (1.f / 64.f);
  float r = rsqrtf(var + 1e-5f);
  x1[n * HD + lane] =
      __float2half(dv * r * ldf(g1, lane, bf) + ldf(b1, lane, bf));
}

// Kernel 3: fused QKV + dense attention, 512 threads, MFMA core (R30).
// R31: W out of LDS. Post-mortem R30: projections read Wl[...] from LDS
// per element -> ~1024 broadcast ds_read_b32 per thread; at 16 waves/CU
// on ONE LDS pipe that's ~30us of issue serialization — the true cause
// of the whole session's 50-54us plateau (KV-packing cut only the ~10%
// inner-loop share; occupancy/regs never touched W reads). Fix: W is
// wave-uniform -> pre-packed f16-pair words in workspace (wpk/bpk),
// indexed uniformly -> scalar-path loads (s_load or broadcast vm), and
// projections via v_dot2_f32_f16 on f16 x1 (256 dot2, 0 LDS per row).
// W-staging phase + its barrier deleted; LDS = Qs/Ks/Vt only (22 KB).
// MFMA core verbatim from R30 (layout-verified by R9's pass).
__global__ __launch_bounds__(512, 2) void k_attn13(
    const __half* __restrict__ x1,
    const unsigned* __restrict__ wpk, const float* __restrict__ bpk,
    bf16* __restrict__ num_t, float* __restrict__ den_t)
{
  const int t = threadIdx.x;
  __shared__ _Float16 Qs[NPG * QS_STR];   // 12 KB
  __shared__ _Float16 Ks[256 * KS_STR];   // 6 KB
  __shared__ _Float16 Vt[DH * VT_STR];    // 4.1 KB (V transposed)
  const int bid = blockIdx.x;
  const int g = bid >> 4, hd = (bid >> 1) & 7, half = bid & 1;
  // qscale = (1/sqrt(8)) * log2(e): softmax via exp2 (folded into Q).
  const float qscale = 0.3535533905932738f * 1.4426950408889634f;
  {
    // ---- K (waves 0-3) or V (waves 4-7) projection for local row t&255 ----
    const int r = t & 255;
    const int m = (t < 256) ? 1 : 2;   // wave-uniform: no divergence
    const uint4* xk4 = (const uint4*)(x1 + (size_t)(g * NPG + half * 256 + r) * HD);
    const unsigned* wb0 = wpk + m * 2048 + hd * 8;   // uniform base
    float acc[DH];
#pragma unroll
    for (int j = 0; j < DH; ++j) acc[j] = bpk[m * 64 + hd * 8 + j];
#pragma unroll
    for (int blk = 0; blk < 8; ++blk) {
      uint4 xp = xk4[blk];             // 8 f16 of x row (4 pairs)
      const unsigned* wb = wb0 + blk * 256;   // kp = blk*4 .. +3
#pragma unroll
      for (int j = 0; j < DH; ++j) {
        acc[j] = fdot2u(xp.x, wb[j], acc[j]);
        acc[j] = fdot2u(xp.y, wb[64 + j], acc[j]);
        acc[j] = fdot2u(xp.z, wb[128 + j], acc[j]);
        acc[j] = fdot2u(xp.w, wb[192 + j], acc[j]);
      }
    }
    if (t < 256) {
      // K row r: 8 f16 packed, two 8B stores (24B row stride).
      unsigned w0 = packh2(acc[0], acc[1]), w1 = packh2(acc[2], acc[3]);
      unsigned w2 = packh2(acc[4], acc[5]), w3 = packh2(acc[6], acc[7]);
      *(uint2*)(Ks + r * KS_STR) = make_uint2(w0, w1);
      *(uint2*)(Ks + r * KS_STR + 4) = make_uint2(w2, w3);
    } else {
      // V row r transposed: 8 scalar f16 stores (2 lanes/bank = free).
#pragma unroll
      for (int j = 0; j < DH; ++j) Vt[j * VT_STR + r] = (_Float16)acc[j];
    }
  }
  {
    // ---- Q projection: row t -> Qs (pre-scaled by qscale) ----
    const uint4* xa4 = (const uint4*)(x1 + (size_t)(g * NPG + t) * HD);
    const unsigned* wb0 = wpk + hd * 8;              // m = 0
    float qa[DH];
#pragma unroll
    for (int j = 0; j < DH; ++j) qa[j] = bpk[hd * 8 + j];
#pragma unroll
    for (int blk = 0; blk < 8; ++blk) {
      uint4 xp = xa4[blk];
      const unsigned* wb = wb0 + blk * 256;
#pragma unroll
      for (int j = 0; j < DH; ++j) {
        qa[j] = fdot2u(xp.x, wb[j], qa[j]);
        qa[j] = fdot2u(xp.y, wb[64 + j], qa[j]);
        qa[j] = fdot2u(xp.z, wb[128 + j], qa[j]);
        qa[j] = fdot2u(xp.w, wb[192 + j], qa[j]);
      }
    }
    unsigned w0 = packh2(qa[0] * qscale, qa[1] * qscale);
    unsigned w1 = packh2(qa[2] * qscale, qa[3] * qscale);
    unsigned w2 = packh2(qa[4] * qscale, qa[5] * qscale);
    unsigned w3 = packh2(qa[6] * qscale, qa[7] * qscale);
    *(uint2*)(Qs + t * QS_STR) = make_uint2(w0, w1);
    *(uint2*)(Qs + t * QS_STR + 4) = make_uint2(w2, w3);
  }
  __syncthreads();   // Qs/Ks/Vt ready
  // ---- MFMA attention: 8 waves x 2 query-tiles of 32 (R30 verbatim) ----
  const int lane = t & 63, wid = t >> 6;
  const int ln = lane & 31, hh = lane >> 5;
  const int plane = half * 8 + hd;
  const size_t obase = (size_t)plane * NN + (size_t)g * NPG;
  v16f zf;
#pragma unroll
  for (int i = 0; i < 16; ++i) zf[i] = 0.f;
#pragma unroll
  for (int qt = 0; qt < 2; ++qt) {
    const int qbase = (wid * 2 + qt) * 32;
    // B-fragment: Q^T -> lane ln holds query qbase+ln, dh 4*hh..+3.
    v4h qf = *(const v4h*)(Qs + (qbase + ln) * QS_STR + 4 * hh);
    v16f oacc = zf;
    float den = 0.f;
#pragma unroll
    for (int kt = 0; kt < 8; ++kt) {
      // A-fragment: K -> lane ln holds key kt*32+ln, dh 4*hh..+3.
      v4h kf = *(const v4h*)(Ks + (kt * 32 + ln) * KS_STR + 4 * hh);
      v16f s = __builtin_amdgcn_mfma_f32_32x32x8f16(kf, qf, zf, 0, 0, 0);
#pragma unroll
      for (int g2 = 0; g2 < 4; ++g2) {
        float e0 = EXP2F(s[4 * g2 + 0]);
        float e1 = EXP2F(s[4 * g2 + 1]);
        float e2 = EXP2F(s[4 * g2 + 2]);
        float e3 = EXP2F(s[4 * g2 + 3]);
        den += (e0 + e1) + (e2 + e3);
        union { unsigned u[2]; v4h v; } pu;
        pu.u[0] = packh2(e0, e1);
        pu.u[1] = packh2(e2, e3);
        // B-fragment: V -> lane ln holds dh col ln&7 (cols 8-31 dup,
        // outputs there unread), keys kt*32+g2*8+4*hh..+3.
        v4h vf = *(const v4h*)(Vt + (ln & 7) * VT_STR + kt * 32 + g2 * 8 + 4 * hh);
        oacc = __builtin_amdgcn_mfma_f32_32x32x8f16(pu.v, vf, oacc, 0, 0, 0);
      }
    }
    // den: lane halves hold complementary key sets of the same query.
    den += __shfl_xor(den, 32);
    if (lane < 32) den_t[obase + qbase + lane] = den;
    // O: C layout -> lane ln<8 holds dh=ln; query per reg & lane-half.
#pragma unroll
    for (int r = 0; r < 16; ++r) {
      const int q = qbase + (r & 3) + 8 * (r >> 2) + 4 * hh;
      if (ln < 8)
        num_t[(obase + q) * 8 + ln] = __float2bfloat16(oacc[r]);
    }
  }
}

// Kernel 4: merge attn halves -> o; y = relu(o @ wo + bo);
// out = LN(x1 + y; g2, b2). 32 nodes/block. x1 now f16 (R31).
__global__ __launch_bounds__(256) void k_out(
    const bf16* __restrict__ num_t, const float* __restrict__ den_t,
    const __half* __restrict__ x1,
    const void* __restrict__ wo, const void* __restrict__ bo,
    const void* __restrict__ g2, const void* __restrict__ b2,
    const int* __restrict__ dflag, void* __restrict__ out)
{
  const int tid = threadIdx.x, lane = tid & 63, wid = tid >> 6;
  const int bf = *dflag;
  __shared__ float wl[HD * HD];
  __shared__ float orow[4][HD];
  for (int i = tid; i < HD * HD; i += 256) wl[i] = ldf(wo, i, bf);
  const float bov = ldf(bo, lane, bf);
  const float g2v = ldf(g2, lane, bf);
  const float b2v = ldf(b2, lane, bf);
  const int hdp = lane >> 3, jp = lane & 7;
  __syncthreads();
#pragma unroll
  for (int r = 0; r < 8; ++r) {
    const int node = blockIdx.x * 32 + r * 4 + wid;
    {
      float nm = b2f(num_t[((size_t)hdp * NN + node) * 8 + jp]) +
                 b2f(num_t[((size_t)(8 + hdp) * NN + node) * 8 + jp]);
      float dn = den_t[(size_t)hdp * NN + node] +
                 den_t[(size_t)(8 + hdp) * NN + node];
      orow[wid][lane] = nm / dn;   // wave-local slot
    }
    float y = bov;
#pragma unroll
    for (int i = 0; i < HD; ++i) y = fmaf(orow[wid][i], wl[i * HD + lane], y);
    float tt = __half2float(x1[node * HD + lane]) + fmaxf(y, 0.f);
    float mu = wave_sum(tt) * (1.f / 64.f);
    float dv = tt - mu;
    float var = wave_sum(dv * dv) * (1.f / 64.f);
    float rr = rsqrtf(var + 1e-5f);
    float res = dv * rr * g2v + b2v;
    if (bf) ((bf16*)out)[node * HD + lane] = __float2bfloat16(res);
    else    ((float*)out)[node * HD + lane] = res;
  }
}

extern "C" void kernel_launch(void* const* d_in, const int* in_sizes, int n_in,
                              void* d_out, int out_size, void* d_ws, size_t ws_size,
                              hipStream_t stream)
{
  const void* x    = d_in[0];
  const void* wgat = d_in[1];
  const void* asrc = d_in[2];
  const void* adst = d_in[3];
  const void* bgat = d_in[4];
  const void* g1   = d_in[5];
  const void* b1   = d_in[6];
  const void* wq   = d_in[7];
  const void* bq   = d_in[8];
  const void* wk   = d_in[9];
  const void* bk   = d_in[10];
  const void* wv   = d_in[11];
  const void* bv   = d_in[12];
  const void* wo   = d_in[13];
  const void* bo   = d_in[14];
  const void* g2   = d_in[15];
  const void* b2   = d_in[16];
  const int*  ei   = (const int*)d_in[17];
  const int E = in_sizes[17] / 2;
  const int* esrc = ei;
  const int* edst = ei + E;

  // Workspace (~7.3 MiB):
  //   [0, 2M):      f16 x1
  //   [2M, 4.62M):  ell (NN*DEGMAX int)    } dead after k_gather;
  //   [4.62M,6.62M):bf16 h                 } k_attn13 overwrites:
  //   [2M, 6M):     bf16 num_t (16 planes * NN * 8)
  //   [6M, 7M):     f32 den_t (16 planes * NN)
  //   [7M, ...):    as_, ad_ (NN f32 each), cur (NN int), flag,
  //                 wpk (6144 u32), bpk (192 f32)
  char* W = (char*)d_ws;
  __half* x1b  = (__half*)W;
  int*   ell   = (int*)(W + (size_t)(2 << 20));
  bf16*  hb    = (bf16*)(W + (size_t)(2 << 20) + (size_t)NN * DEGMAX * 4);
  bf16*  num_t = (bf16*)(W + (size_t)(2 << 20));
  float* den_t = (float*)(W + (size_t)(6 << 20));
  float* as_   = (float*)(W + (size_t)(7 << 20));
  float* ad_   = as_ + NN;
  int*   cur   = (int*)(ad_ + NN);
  int*   flag  = cur + NN;
  unsigned* wpk = (unsigned*)(flag + 1);
  float* bpk   = (float*)(wpk + 3 * 32 * 64);

  hipMemsetAsync(cur, 0, NN * sizeof(int), stream);
  k_build  <<<NN / 16, 256, 0, stream>>>(x, wgat, asrc, adst, esrc, edst, E,
                                         cur, ell, hb, as_, ad_, flag);
  k_gather <<<NN / 4, 256, 0, stream>>>(x, cur, ell, as_, ad_, hb,
                                        bgat, g1, b1,
                                        wq, bq, wk, bk, wv, bv,
                                        flag, wpk, bpk, x1b);
  k_attn13 <<<BG * NHEADS * 2, 512, 0, stream>>>(x1b, wpk, bpk, num_t, den_t);
  k_out    <<<NN / 32, 256, 0, stream>>>(num_t, den_t, x1b, wo, bo, g2, b2,
                                         flag, d_out);
}

// Round 11
// 177.712 us; speedup vs baseline: 1.0132x; 1.0132x over previous
//
#include <hip/hip_runtime.h>
#include <hip/hip_bf16.h>
#include <hip/hip_fp16.h>

// Problem constants (from reference)
#define NN     16384   // nodes
#define HD     64      // hidden dim
#define BG     32      // graphs
#define NPG    512     // nodes per graph
#define NHEADS 8
#define DH     8
#define DEGMAX 40      // ELL width; deg ~ Poisson(16), P(>40) ~ 3e-8/node

// R30 MFMA attn LDS geometry (f16):
//   Qs[512][12], Ks[256][12]: row stride 12 f16 = 24B -> b64 fragment reads
//   8B-aligned; bank stride 6 -> only 2-way aliasing (free, m136).
//   Vt[8][264]: V transposed; row stride 528B -> the 8 dh-rows hit banks
//   {0,4,8,...,28}; b64 frag reads conflict-free; lanes 8-31 broadcast.
#define QS_STR 12
#define KS_STR 12
#define VT_STR 264

typedef __hip_bfloat16 bf16;
typedef _Float16 v4h __attribute__((ext_vector_type(4)));
typedef float v16f __attribute__((ext_vector_type(16)));

#if defined(__has_builtin)
#if __has_builtin(__builtin_amdgcn_exp2f)
#define EXP2F(x) __builtin_amdgcn_exp2f(x)
#else
#define EXP2F(x) exp2f(x)
#endif
#if __has_builtin(__builtin_amdgcn_fdot2)
#define HAS_FDOT2 1
#endif
#else
#define EXP2F(x) exp2f(x)
#endif

#ifdef HAS_FDOT2
typedef _Float16 hvec2 __attribute__((ext_vector_type(2)));
#endif

// dot2 on two packed-f16 u32 words, f32 accumulate (fallback: plain f32).
__device__ __forceinline__ float fdot2u(unsigned a, unsigned b, float c) {
#ifdef HAS_FDOT2
  union { unsigned u; hvec2 v; } x, y;
  x.u = a; y.u = b;
  return __builtin_amdgcn_fdot2(x.v, y.v, c, false);
#else
  union { unsigned u; __half2 h; } x, y;
  x.u = a; y.u = b;
  return fmaf(__low2float(x.h), __low2float(y.h),
              fmaf(__high2float(x.h), __high2float(y.h), c));
#endif
}

__device__ __forceinline__ float b2f(bf16 v) { return __bfloat162float(v); }

// Flag-steered input load: bf=1 -> buffer is bf16, bf=0 -> fp32.
__device__ __forceinline__ float ldf(const void* p, int i, int bf) {
  return bf ? __bfloat162float(((const bf16*)p)[i]) : ((const float*)p)[i];
}

__device__ __forceinline__ float wave_sum(float v) {
#pragma unroll
  for (int off = 32; off > 0; off >>= 1) v += __shfl_xor(v, off);
  return v;
}

__device__ __forceinline__ void unpack8(uint4 u, float* f) {
  f[0] = __uint_as_float(u.x << 16); f[1] = __uint_as_float(u.x & 0xffff0000u);
  f[2] = __uint_as_float(u.y << 16); f[3] = __uint_as_float(u.y & 0xffff0000u);
  f[4] = __uint_as_float(u.z << 16); f[5] = __uint_as_float(u.z & 0xffff0000u);
  f[6] = __uint_as_float(u.w << 16); f[7] = __uint_as_float(u.w & 0xffff0000u);
}

__device__ __forceinline__ unsigned short bfbits(float f) {
  bf16 b = __float2bfloat16(f);
  return *(unsigned short*)&b;
}

__device__ __forceinline__ unsigned packh2(float a, float b) {
  union { unsigned u; __half2 h; } z;
  z.h = __floats2half2_rn(a, b);
  return z.u;
}

// Per-block dtype detection (bf16 vs fp32 inputs) — only k_build pays this
// (256 samples; bf16 scores ~256, fp32 ~51 — wide margin); publishes flag.
__device__ __forceinline__ int detect_bf(const unsigned short* xr, int tid, int nt) {
  __shared__ int s_cnt;
  if (tid == 0) s_cnt = 0;
  __syncthreads();
  int sane = 0;
  for (int i = tid; i < 256; i += nt) {
    int e = (xr[2 * i] >> 7) & 0xFF;
    sane += (e >= 100 && e <= 150) ? 1 : 0;
  }
  if (sane) atomicAdd(&s_cnt, sane);
  __syncthreads();
  return s_cnt > 180;
}

// Kernel 1: h = x @ w_gat (bf16 out); as_/ad_ logit halves; + fused ELL
// scatter; + publish dtype flag. 16 nodes/block (champion config —
// 32/block regressed in R20: doubles the edge-scatter trip count).
__global__ __launch_bounds__(256) void k_build(
    const void* __restrict__ x, const void* __restrict__ w,
    const void* __restrict__ asrc, const void* __restrict__ adst,
    const int* __restrict__ esrc, const int* __restrict__ edst, int E,
    int* __restrict__ cur, int* __restrict__ ell,
    bf16* __restrict__ h, float* __restrict__ as_, float* __restrict__ ad_,
    int* __restrict__ flagp)
{
  const int tid = threadIdx.x, lane = tid & 63, wid = tid >> 6;
  const int bf = detect_bf((const unsigned short*)x, tid, 256);
  if (tid == 0 && blockIdx.x == 0) *flagp = bf;
  __shared__ float wl[HD * HD];
  __shared__ float xr[4][HD];
  {
    for (int e = blockIdx.x * 256 + tid; e < E; e += gridDim.x * 256) {
      int d = edst[e];
      int k = atomicAdd(&cur[d], 1);
      if (k < DEGMAX) ell[d * DEGMAX + k] = esrc[e];
    }
  }
  for (int i = tid; i < HD * HD; i += 256) wl[i] = ldf(w, i, bf);
  const float av = ldf(asrc, lane, bf), dv_ = ldf(adst, lane, bf);
  __syncthreads();
#pragma unroll
  for (int r = 0; r < 4; ++r) {
    const int node = blockIdx.x * 16 + r * 4 + wid;
    xr[wid][lane] = ldf(x, node * HD + lane, bf);   // wave-local slot
    float hj = 0.f;
#pragma unroll
    for (int i = 0; i < HD; ++i) hj = fmaf(xr[wid][i], wl[i * HD + lane], hj);
    float pa = wave_sum(hj * av);
    float pd = wave_sum(hj * dv_);
    h[node * HD + lane] = __float2bfloat16(hj);
    if (lane == 0) { as_[node] = pa; ad_[node] = pd; }
  }
}

// Kernel 2: wave-per-node GAT gather (ELL) + bias + relu + residual + LN1 -> x1
// R31: x1 stored f16; blocks 0-4 pre-pack [Wq|Wk|Wv]/biases for k_attn13.
__global__ __launch_bounds__(256) void k_gather(
    const void* __restrict__ x, const int* __restrict__ cur,
    const int* __restrict__ ell, const float* __restrict__ as_,
    const float* __restrict__ ad_, const bf16* __restrict__ h,
    const void* __restrict__ bg, const void* __restrict__ g1,
    const void* __restrict__ b1,
    const void* __restrict__ wq, const void* __restrict__ bq,
    const void* __restrict__ wk, const void* __restrict__ bk,
    const void* __restrict__ wv, const void* __restrict__ bv,
    const int* __restrict__ dflag,
    unsigned* __restrict__ wpk, float* __restrict__ bpk,
    __half* __restrict__ x1)
{
  const int tid = threadIdx.x, lane = tid & 63, wid = tid >> 6;
  const int bf = *dflag;
  // ---- QKV weight/bias pre-pack for k_attn13 (blocks 0-4 only) ----
  if (blockIdx.x < 4) {
    for (int idx = blockIdx.x * 256 + tid; idx < 3 * 32 * 64; idx += 1024) {
      int m = idx >> 11;            // 0..2 (2048 words per matrix)
      int r = idx & 2047;
      int kp = r >> 6, col = r & 63;
      const void* ws = (m == 0) ? wq : (m == 1) ? wk : wv;
      wpk[idx] = packh2(ldf(ws, (2 * kp) * HD + col, bf),
                        ldf(ws, (2 * kp + 1) * HD + col, bf));
    }
  } else if (blockIdx.x == 4 && tid < 192) {
    int m = tid >> 6, col = tid & 63;
    const void* bs = (m == 0) ? bq : (m == 1) ? bk : bv;
    bpk[tid] = ldf(bs, col, bf);
  }
  const int n = blockIdx.x * 4 + wid;
  const float adn = ad_[n];
  float e0 = as_[n] + adn;
  e0 = e0 > 0.f ? e0 : 0.2f * e0;
  float den = __expf(fminf(e0, 30.f));
  float num = den * b2f(h[n * HD + lane]);
  const int deg = min(cur[n], DEGMAX);
  const int* row = ell + n * DEGMAX;
  int i = 0;
  for (; i + 8 <= deg; i += 8) {
    int s[8];
#pragma unroll
    for (int k = 0; k < 8; ++k) s[k] = row[i + k];
    float a[8], hh[8];
#pragma unroll
    for (int k = 0; k < 8; ++k) a[k] = as_[s[k]];
#pragma unroll
    for (int k = 0; k < 8; ++k) hh[k] = b2f(h[s[k] * HD + lane]);
#pragma unroll
    for (int k = 0; k < 8; ++k) {
      float e = a[k] + adn;
      e = e > 0.f ? e : 0.2f * e;
      float p = __expf(fminf(e, 30.f));
      den += p;
      num = fmaf(p, hh[k], num);
    }
  }
  for (; i + 4 <= deg; i += 4) {
    int s0 = row[i], s1 = row[i + 1], s2 = row[i + 2], s3 = row[i + 3];
    float a0 = as_[s0], a1 = as_[s1], a2 = as_[s2], a3 = as_[s3];
    float h0 = b2f(h[s0 * HD + lane]), h1 = b2f(h[s1 * HD + lane]);
    float h2 = b2f(h[s2 * HD + lane]), h3 = b2f(h[s3 * HD + lane]);
    float e_0 = a0 + adn; e_0 = e_0 > 0.f ? e_0 : 0.2f * e_0;
    float e_1 = a1 + adn; e_1 = e_1 > 0.f ? e_1 : 0.2f * e_1;
    float e_2 = a2 + adn; e_2 = e_2 > 0.f ? e_2 : 0.2f * e_2;
    float e_3 = a3 + adn; e_3 = e_3 > 0.f ? e_3 : 0.2f * e_3;
    float p0 = __expf(fminf(e_0, 30.f)), p1 = __expf(fminf(e_1, 30.f));
    float p2 = __expf(fminf(e_2, 30.f)), p3 = __expf(fminf(e_3, 30.f));
    den += p0 + p1 + p2 + p3;
    num = fmaf(p0, h0, num); num = fmaf(p1, h1, num);
    num = fmaf(p2, h2, num); num = fmaf(p3, h3, num);
  }
  for (; i < deg; ++i) {
    int s = row[i];
    float e = as_[s] + adn;
    e = e > 0.f ? e : 0.2f * e;
    float p = __expf(fminf(e, 30.f));
    den += p;
    num = fmaf(p, b2f(h[s * HD + lane]), num);
  }
  float v = num / (den + 1e-16f) + ldf(bg, lane, bf);
  v = fmaxf(v, 0.f) + ldf(x, n * HD + lane, bf);
  float mu = wave_sum(v) * (1.f / 64.f);
  float dv = v - mu;
  float var = wave_sum(dv * dv) * (1.f / 64.f);
  float r = rsqrtf(var + 1e-5f);
  x1[n * HD + lane] =
      __float2half(dv * r * ldf(g1, lane, bf) + ldf(b1, lane, bf));
}

// Kernel 3: fused QKV + dense attention, 512 threads, MFMA core.
// R31 structure, frozen this round (R32 changes k_out only).
__global__ __launch_bounds__(512, 2) void k_attn13(
    const __half* __restrict__ x1,
    const unsigned* __restrict__ wpk, const float* __restrict__ bpk,
    bf16* __restrict__ num_t, float* __restrict__ den_t)
{
  const int t = threadIdx.x;
  __shared__ _Float16 Qs[NPG * QS_STR];   // 12 KB
  __shared__ _Float16 Ks[256 * KS_STR];   // 6 KB
  __shared__ _Float16 Vt[DH * VT_STR];    // 4.1 KB (V transposed)
  const int bid = blockIdx.x;
  const int g = bid >> 4, hd = (bid >> 1) & 7, half = bid & 1;
  // qscale = (1/sqrt(8)) * log2(e): softmax via exp2 (folded into Q).
  const float qscale = 0.3535533905932738f * 1.4426950408889634f;
  {
    // ---- K (waves 0-3) or V (waves 4-7) projection for local row t&255 ----
    const int r = t & 255;
    const int m = (t < 256) ? 1 : 2;   // wave-uniform: no divergence
    const uint4* xk4 = (const uint4*)(x1 + (size_t)(g * NPG + half * 256 + r) * HD);
    const unsigned* wb0 = wpk + m * 2048 + hd * 8;   // uniform base
    float acc[DH];
#pragma unroll
    for (int j = 0; j < DH; ++j) acc[j] = bpk[m * 64 + hd * 8 + j];
#pragma unroll
    for (int blk = 0; blk < 8; ++blk) {
      uint4 xp = xk4[blk];             // 8 f16 of x row (4 pairs)
      const unsigned* wb = wb0 + blk * 256;   // kp = blk*4 .. +3
#pragma unroll
      for (int j = 0; j < DH; ++j) {
        acc[j] = fdot2u(xp.x, wb[j], acc[j]);
        acc[j] = fdot2u(xp.y, wb[64 + j], acc[j]);
        acc[j] = fdot2u(xp.z, wb[128 + j], acc[j]);
        acc[j] = fdot2u(xp.w, wb[192 + j], acc[j]);
      }
    }
    if (t < 256) {
      // K row r: 8 f16 packed, two 8B stores (24B row stride).
      unsigned w0 = packh2(acc[0], acc[1]), w1 = packh2(acc[2], acc[3]);
      unsigned w2 = packh2(acc[4], acc[5]), w3 = packh2(acc[6], acc[7]);
      *(uint2*)(Ks + r * KS_STR) = make_uint2(w0, w1);
      *(uint2*)(Ks + r * KS_STR + 4) = make_uint2(w2, w3);
    } else {
      // V row r transposed: 8 scalar f16 stores (2 lanes/bank = free).
#pragma unroll
      for (int j = 0; j < DH; ++j) Vt[j * VT_STR + r] = (_Float16)acc[j];
    }
  }
  {
    // ---- Q projection: row t -> Qs (pre-scaled by qscale) ----
    const uint4* xa4 = (const uint4*)(x1 + (size_t)(g * NPG + t) * HD);
    const unsigned* wb0 = wpk + hd * 8;              // m = 0
    float qa[DH];
#pragma unroll
    for (int j = 0; j < DH; ++j) qa[j] = bpk[hd * 8 + j];
#pragma unroll
    for (int blk = 0; blk < 8; ++blk) {
      uint4 xp = xa4[blk];
      const unsigned* wb = wb0 + blk * 256;
#pragma unroll
      for (int j = 0; j < DH; ++j) {
        qa[j] = fdot2u(xp.x, wb[j], qa[j]);
        qa[j] = fdot2u(xp.y, wb[64 + j], qa[j]);
        qa[j] = fdot2u(xp.z, wb[128 + j], qa[j]);
        qa[j] = fdot2u(xp.w, wb[192 + j], qa[j]);
      }
    }
    unsigned w0 = packh2(qa[0] * qscale, qa[1] * qscale);
    unsigned w1 = packh2(qa[2] * qscale, qa[3] * qscale);
    unsigned w2 = packh2(qa[4] * qscale, qa[5] * qscale);
    unsigned w3 = packh2(qa[6] * qscale, qa[7] * qscale);
    *(uint2*)(Qs + t * QS_STR) = make_uint2(w0, w1);
    *(uint2*)(Qs + t * QS_STR + 4) = make_uint2(w2, w3);
  }
  __syncthreads();   // Qs/Ks/Vt ready
  // ---- MFMA attention: 8 waves x 2 query-tiles of 32 (R30 verbatim) ----
  const int lane = t & 63, wid = t >> 6;
  const int ln = lane & 31, hh = lane >> 5;
  const int plane = half * 8 + hd;
  const size_t obase = (size_t)plane * NN + (size_t)g * NPG;
  v16f zf;
#pragma unroll
  for (int i = 0; i < 16; ++i) zf[i] = 0.f;
#pragma unroll
  for (int qt = 0; qt < 2; ++qt) {
    const int qbase = (wid * 2 + qt) * 32;
    // B-fragment: Q^T -> lane ln holds query qbase+ln, dh 4*hh..+3.
    v4h qf = *(const v4h*)(Qs + (qbase + ln) * QS_STR + 4 * hh);
    v16f oacc = zf;
    float den = 0.f;
#pragma unroll
    for (int kt = 0; kt < 8; ++kt) {
      // A-fragment: K -> lane ln holds key kt*32+ln, dh 4*hh..+3.
      v4h kf = *(const v4h*)(Ks + (kt * 32 + ln) * KS_STR + 4 * hh);
      v16f s = __builtin_amdgcn_mfma_f32_32x32x8f16(kf, qf, zf, 0, 0, 0);
#pragma unroll
      for (int g2 = 0; g2 < 4; ++g2) {
        float e0 = EXP2F(s[4 * g2 + 0]);
        float e1 = EXP2F(s[4 * g2 + 1]);
        float e2 = EXP2F(s[4 * g2 + 2]);
        float e3 = EXP2F(s[4 * g2 + 3]);
        den += (e0 + e1) + (e2 + e3);
        union { unsigned u[2]; v4h v; } pu;
        pu.u[0] = packh2(e0, e1);
        pu.u[1] = packh2(e2, e3);
        // B-fragment: V -> lane ln holds dh col ln&7 (cols 8-31 dup,
        // outputs there unread), keys kt*32+g2*8+4*hh..+3.
        v4h vf = *(const v4h*)(Vt + (ln & 7) * VT_STR + kt * 32 + g2 * 8 + 4 * hh);
        oacc = __builtin_amdgcn_mfma_f32_32x32x8f16(pu.v, vf, oacc, 0, 0, 0);
      }
    }
    // den: lane halves hold complementary key sets of the same query.
    den += __shfl_xor(den, 32);
    if (lane < 32) den_t[obase + qbase + lane] = den;
    // O: C layout -> lane ln<8 holds dh=ln; query per reg & lane-half.
#pragma unroll
    for (int r = 0; r < 16; ++r) {
      const int q = qbase + (r & 3) + 8 * (r >> 2) + 4 * hh;
      if (ln < 8)
        num_t[(obase + q) * 8 + ln] = __float2bfloat16(oacc[r]);
    }
  }
}

// Kernel 4: merge attn halves -> o; y = relu(o @ wo + bo); out = LN(x1+y).
// R32: MFMA rewrite. Post-mortem R31: k_out's scalar matvec does 1024 LDS
// b32 reads/thread (wl + orow broadcast per FMA); 8 waves/CU x 1024 x
// ~5.8cy on the single LDS pipe ~= 20us — same signature MFMA cured in
// k_attn13 (R9: -15us). New shape: 1 wave per 32-node tile (512 blocks x
// 64 thr), O[32x64] @ wo[64x64] = 16 x mfma_32x32x8_f16 (layouts verified
// R9/R30). A-frag from num_t/den_t: dim kt*8+4hh+q <-> head kt, j=4hh+q.
// B-frag: coalesced global wo reads (L1-hot, no LDS at all). LN epilogue
// via within-32-half shfl_xor (C row = (reg&3)+8(reg>>2)+4(lane>>5) lives
// entirely in one half). f16 o/wo quantization ~1e-3 << bf16 out rounding.
__global__ __launch_bounds__(64) void k_out(
    const bf16* __restrict__ num_t, const float* __restrict__ den_t,
    const __half* __restrict__ x1,
    const void* __restrict__ wo, const void* __restrict__ bo,
    const void* __restrict__ g2, const void* __restrict__ b2,
    const int* __restrict__ dflag, void* __restrict__ out)
{
  const int t = threadIdx.x;
  const int bf = *dflag;
  const int ln = t & 31, hh = t >> 5;
  const int base = blockIdx.x * 32;
  const int n = base + ln;
  v16f c0, c1;
#pragma unroll
  for (int i = 0; i < 16; ++i) { c0[i] = 0.f; c1[i] = 0.f; }
#pragma unroll
  for (int kt = 0; kt < 8; ++kt) {
    // A-frag: o[node n][dims kt*8+4hh .. +3] = (num_lo+num_hi)/den
    union { uint2 u; unsigned short s[4]; } L, H;
    L.u = *(const uint2*)(num_t + ((size_t)kt * NN + n) * 8 + 4 * hh);
    H.u = *(const uint2*)(num_t + ((size_t)(8 + kt) * NN + n) * 8 + 4 * hh);
    float den = den_t[(size_t)kt * NN + n] + den_t[(size_t)(8 + kt) * NN + n];
    float rden = 1.f / den;
    float o0 = (__uint_as_float((unsigned)L.s[0] << 16) +
                __uint_as_float((unsigned)H.s[0] << 16)) * rden;
    float o1 = (__uint_as_float((unsigned)L.s[1] << 16) +
                __uint_as_float((unsigned)H.s[1] << 16)) * rden;
    float o2 = (__uint_as_float((unsigned)L.s[2] << 16) +
                __uint_as_float((unsigned)H.s[2] << 16)) * rden;
    float o3 = (__uint_as_float((unsigned)L.s[3] << 16) +
                __uint_as_float((unsigned)H.s[3] << 16)) * rden;
    union { unsigned u[2]; v4h v; } A;
    A.u[0] = packh2(o0, o1);
    A.u[1] = packh2(o2, o3);
    // B-frags: wo rows kt*8+4hh..+3, cols ln (ct=0) and 32+ln (ct=1).
    const int kr = kt * 8 + 4 * hh;
    union { unsigned u[2]; v4h v; } B0, B1;
    B0.u[0] = packh2(ldf(wo, (kr + 0) * HD + ln, bf),
                     ldf(wo, (kr + 1) * HD + ln, bf));
    B0.u[1] = packh2(ldf(wo, (kr + 2) * HD + ln, bf),
                     ldf(wo, (kr + 3) * HD + ln, bf));
    B1.u[0] = packh2(ldf(wo, (kr + 0) * HD + 32 + ln, bf),
                     ldf(wo, (kr + 1) * HD + 32 + ln, bf));
    B1.u[1] = packh2(ldf(wo, (kr + 2) * HD + 32 + ln, bf),
                     ldf(wo, (kr + 3) * HD + 32 + ln, bf));
    c0 = __builtin_amdgcn_mfma_f32_32x32x8f16(A.v, B0.v, c0, 0, 0, 0);
    c1 = __builtin_amdgcn_mfma_f32_32x32x8f16(A.v, B1.v, c1, 0, 0, 0);
  }
  // Epilogue: bias+relu+residual+LN per C row (row fully in one 32-half).
  const float bo0 = ldf(bo, ln, bf),      bo1 = ldf(bo, 32 + ln, bf);
  const float g20 = ldf(g2, ln, bf),      g21 = ldf(g2, 32 + ln, bf);
  const float b20 = ldf(b2, ln, bf),      b21 = ldf(b2, 32 + ln, bf);
#pragma unroll
  for (int r = 0; r < 16; ++r) {
    const int node = base + (r & 3) + 8 * (r >> 2) + 4 * hh;
    float t0 = __half2float(x1[node * HD + ln]) + fmaxf(c0[r] + bo0, 0.f);
    float t1 = __half2float(x1[node * HD + 32 + ln]) + fmaxf(c1[r] + bo1, 0.f);
    float s = t0 + t1;
#pragma unroll
    for (int off = 1; off < 32; off <<= 1) s += __shfl_xor(s, off);
    const float mu = s * (1.f / 64.f);
    const float d0 = t0 - mu, d1 = t1 - mu;
    float v = d0 * d0 + d1 * d1;
#pragma unroll
    for (int off = 1; off < 32; off <<= 1) v += __shfl_xor(v, off);
    const float rr = rsqrtf(v * (1.f / 64.f) + 1e-5f);
    const float r0 = d0 * rr * g20 + b20;
    const float r1 = d1 * rr * g21 + b21;
    if (bf) {
      ((bf16*)out)[node * HD + ln]      = __float2bfloat16(r0);
      ((bf16*)out)[node * HD + 32 + ln] = __float2bfloat16(r1);
    } else {
      ((float*)out)[node * HD + ln]      = r0;
      ((float*)out)[node * HD + 32 + ln] = r1;
    }
  }
}

extern "C" void kernel_launch(void* const* d_in, const int* in_sizes, int n_in,
                              void* d_out, int out_size, void* d_ws, size_t ws_size,
                              hipStream_t stream)
{
  const void* x    = d_in[0];
  const void* wgat = d_in[1];
  const void* asrc = d_in[2];
  const void* adst = d_in[3];
  const void* bgat = d_in[4];
  const void* g1   = d_in[5];
  const void* b1   = d_in[6];
  const void* wq   = d_in[7];
  const void* bq   = d_in[8];
  const void* wk   = d_in[9];
  const void* bk   = d_in[10];
  const void* wv   = d_in[11];
  const void* bv   = d_in[12];
  const void* wo   = d_in[13];
  const void* bo   = d_in[14];
  const void* g2   = d_in[15];
  const void* b2   = d_in[16];
  const int*  ei   = (const int*)d_in[17];
  const int E = in_sizes[17] / 2;
  const int* esrc = ei;
  const int* edst = ei + E;

  // Workspace (~7.3 MiB):
  //   [0, 2M):      f16 x1
  //   [2M, 4.62M):  ell (NN*DEGMAX int)    } dead after k_gather;
  //   [4.62M,6.62M):bf16 h                 } k_attn13 overwrites:
  //   [2M, 6M):     bf16 num_t (16 planes * NN * 8)
  //   [6M, 7M):     f32 den_t (16 planes * NN)
  //   [7M, ...):    as_, ad_ (NN f32 each), cur (NN int), flag,
  //                 wpk (6144 u32), bpk (192 f32)
  char* W = (char*)d_ws;
  __half* x1b  = (__half*)W;
  int*   ell   = (int*)(W + (size_t)(2 << 20));
  bf16*  hb    = (bf16*)(W + (size_t)(2 << 20) + (size_t)NN * DEGMAX * 4);
  bf16*  num_t = (bf16*)(W + (size_t)(2 << 20));
  float* den_t = (float*)(W + (size_t)(6 << 20));
  float* as_   = (float*)(W + (size_t)(7 << 20));
  float* ad_   = as_ + NN;
  int*   cur   = (int*)(ad_ + NN);
  int*   flag  = cur + NN;
  unsigned* wpk = (unsigned*)(flag + 1);
  float* bpk   = (float*)(wpk + 3 * 32 * 64);

  hipMemsetAsync(cur, 0, NN * sizeof(int), stream);
  k_build  <<<NN / 16, 256, 0, stream>>>(x, wgat, asrc, adst, esrc, edst, E,
                                         cur, ell, hb, as_, ad_, flag);
  k_gather <<<NN / 4, 256, 0, stream>>>(x, cur, ell, as_, ad_, hb,
                                        bgat, g1, b1,
                                        wq, bq, wk, bk, wv, bv,
                                        flag, wpk, bpk, x1b);
  k_attn13 <<<BG * NHEADS * 2, 512, 0, stream>>>(x1b, wpk, bpk, num_t, den_t);
  k_out    <<<NN / 32, 64, 0, stream>>>(num_t, den_t, x1b, wo, bo, g2, b2,
                                        flag, d_out);
}

// Round 12
// 173.664 us; speedup vs baseline: 1.0368x; 1.0233x over previous
//
#include <hip/hip_runtime.h>
#include <hip/hip_bf16.h>
#include <hip/hip_fp16.h>

// Problem constants (from reference)
#define NN     16384   // nodes
#define HD     64      // hidden dim
#define BG     32      // graphs
#define NPG    512     // nodes per graph
#define NHEADS 8
#define DH     8
#define DEGMAX 40      // ELL width; deg ~ Poisson(16), P(>40) ~ 3e-8/node

// R30 MFMA attn LDS geometry (f16):
//   Qs[512][12], Ks[256][12]: row stride 12 f16 = 24B -> b64 fragment reads
//   8B-aligned; bank stride 6 -> only 2-way aliasing (free, m136).
//   Vt[8][264]: V transposed; row stride 528B -> the 8 dh-rows hit banks
//   {0,4,8,...,28}; b64 frag reads conflict-free; lanes 8-31 broadcast.
#define QS_STR 12
#define KS_STR 12
#define VT_STR 264

typedef __hip_bfloat16 bf16;
typedef _Float16 v4h __attribute__((ext_vector_type(4)));
typedef float v16f __attribute__((ext_vector_type(16)));

#if defined(__has_builtin)
#if __has_builtin(__builtin_amdgcn_exp2f)
#define EXP2F(x) __builtin_amdgcn_exp2f(x)
#else
#define EXP2F(x) exp2f(x)
#endif
#if __has_builtin(__builtin_amdgcn_fdot2)
#define HAS_FDOT2 1
#endif
#else
#define EXP2F(x) exp2f(x)
#endif

#ifdef HAS_FDOT2
typedef _Float16 hvec2 __attribute__((ext_vector_type(2)));
#endif

// dot2 on two packed-f16 u32 words, f32 accumulate (fallback: plain f32).
__device__ __forceinline__ float fdot2u(unsigned a, unsigned b, float c) {
#ifdef HAS_FDOT2
  union { unsigned u; hvec2 v; } x, y;
  x.u = a; y.u = b;
  return __builtin_amdgcn_fdot2(x.v, y.v, c, false);
#else
  union { unsigned u; __half2 h; } x, y;
  x.u = a; y.u = b;
  return fmaf(__low2float(x.h), __low2float(y.h),
              fmaf(__high2float(x.h), __high2float(y.h), c));
#endif
}

__device__ __forceinline__ float b2f(bf16 v) { return __bfloat162float(v); }

// Flag-steered input load: bf=1 -> buffer is bf16, bf=0 -> fp32.
__device__ __forceinline__ float ldf(const void* p, int i, int bf) {
  return bf ? __bfloat162float(((const bf16*)p)[i]) : ((const float*)p)[i];
}

__device__ __forceinline__ float wave_sum(float v) {
#pragma unroll
  for (int off = 32; off > 0; off >>= 1) v += __shfl_xor(v, off);
  return v;
}

__device__ __forceinline__ unsigned short bfbits(float f) {
  bf16 b = __float2bfloat16(f);
  return *(unsigned short*)&b;
}

__device__ __forceinline__ unsigned packh2(float a, float b) {
  union { unsigned u; __half2 h; } z;
  z.h = __floats2half2_rn(a, b);
  return z.u;
}

// Kernel 1: h = x @ w_gat + as_/ad_ logit halves + fused ELL scatter +
// dtype-flag publish.
// R33: MFMA rewrite. Post-mortem R32: k_build's scalar matvec is the last
// kernel with the per-lane-LDS-matvec signature (512 broadcast ds_read
// per thread at 16 waves/CU ~= 20us on the LDS pipe, + scatter atomics).
// New shape (cloned from the twice-verified R32 k_out pattern): 512
// blocks x 64 thr, one wave per 32-node tile; h[32x64] = x[32x64] @ w
// via 16 x mfma_32x32x8_f16; ZERO LDS. as_/ad_ from C-regs via 32-half
// shfl reductions. Edge scatter grid-strides the same grid (8/thread).
// detect_bf is wave-local (shfl reduce, no shared).
__global__ __launch_bounds__(64) void k_build(
    const void* __restrict__ x, const void* __restrict__ w,
    const void* __restrict__ asrc, const void* __restrict__ adst,
    const int* __restrict__ esrc, const int* __restrict__ edst, int E,
    int* __restrict__ cur, int* __restrict__ ell,
    bf16* __restrict__ h, float* __restrict__ as_, float* __restrict__ ad_,
    int* __restrict__ flagp)
{
  const int t = threadIdx.x;          // 0..63, one wave
  const int ln = t & 31, hh = t >> 5;
  // ---- dtype detect: 256 exponent samples, wave shfl reduce ----
  int sane = 0;
  {
    const unsigned short* xr = (const unsigned short*)x;
    for (int i = t; i < 256; i += 64) {
      int e = (xr[2 * i] >> 7) & 0xFF;
      sane += (e >= 100 && e <= 150) ? 1 : 0;
    }
#pragma unroll
    for (int off = 32; off > 0; off >>= 1) sane += __shfl_xor(sane, off);
  }
  const int bf = sane > 180;
  if (t == 0 && blockIdx.x == 0) *flagp = bf;
  // ---- edge scatter: 8 grid-stride iterations ----
  for (int e = blockIdx.x * 64 + t; e < E; e += gridDim.x * 64) {
    int d = edst[e];
    int k = atomicAdd(&cur[d], 1);
    if (k < DEGMAX) ell[d * DEGMAX + k] = esrc[e];
  }
  // ---- MFMA: h[base..base+31][0:64] = x-rows @ w (layouts = R32 k_out) ----
  const int base = blockIdx.x * 32;
  v16f c0, c1;
#pragma unroll
  for (int i = 0; i < 16; ++i) { c0[i] = 0.f; c1[i] = 0.f; }
#pragma unroll
  for (int kt = 0; kt < 8; ++kt) {
    const int kr = kt * 8 + 4 * hh;
    // A-frag: row = node base+ln, k-dims kr..kr+3.
    union { unsigned u[2]; v4h v; } A, B0, B1;
    const int xb = (base + ln) * HD + kr;
    A.u[0] = packh2(ldf(x, xb + 0, bf), ldf(x, xb + 1, bf));
    A.u[1] = packh2(ldf(x, xb + 2, bf), ldf(x, xb + 3, bf));
    // B-frags: w rows kr..kr+3, cols ln and 32+ln.
    B0.u[0] = packh2(ldf(w, (kr + 0) * HD + ln, bf),
                     ldf(w, (kr + 1) * HD + ln, bf));
    B0.u[1] = packh2(ldf(w, (kr + 2) * HD + ln, bf),
                     ldf(w, (kr + 3) * HD + ln, bf));
    B1.u[0] = packh2(ldf(w, (kr + 0) * HD + 32 + ln, bf),
                     ldf(w, (kr + 1) * HD + 32 + ln, bf));
    B1.u[1] = packh2(ldf(w, (kr + 2) * HD + 32 + ln, bf),
                     ldf(w, (kr + 3) * HD + 32 + ln, bf));
    c0 = __builtin_amdgcn_mfma_f32_32x32x8f16(A.v, B0.v, c0, 0, 0, 0);
    c1 = __builtin_amdgcn_mfma_f32_32x32x8f16(A.v, B1.v, c1, 0, 0, 0);
  }
  // ---- epilogue: store h (bf16); as_/ad_ via 32-half reductions ----
  const float av0 = ldf(asrc, ln, bf), av1 = ldf(asrc, 32 + ln, bf);
  const float dv0 = ldf(adst, ln, bf), dv1 = ldf(adst, 32 + ln, bf);
#pragma unroll
  for (int r = 0; r < 16; ++r) {
    const int node = base + (r & 3) + 8 * (r >> 2) + 4 * hh;
    h[node * HD + ln]      = __float2bfloat16(c0[r]);
    h[node * HD + 32 + ln] = __float2bfloat16(c1[r]);
    float pa = c0[r] * av0 + c1[r] * av1;
    float pd = c0[r] * dv0 + c1[r] * dv1;
#pragma unroll
    for (int off = 16; off > 0; off >>= 1) {
      pa += __shfl_xor(pa, off);
      pd += __shfl_xor(pd, off);
    }
    if (ln == 0) { as_[node] = pa; ad_[node] = pd; }
  }
}

// Kernel 2: wave-per-node GAT gather (ELL) + bias + relu + residual + LN1 -> x1
// R31: x1 stored f16; blocks 0-4 pre-pack [Wq|Wk|Wv]/biases for k_attn13.
// Frozen this round (R33 changes k_build only).
__global__ __launch_bounds__(256) void k_gather(
    const void* __restrict__ x, const int* __restrict__ cur,
    const int* __restrict__ ell, const float* __restrict__ as_,
    const float* __restrict__ ad_, const bf16* __restrict__ h,
    const void* __restrict__ bg, const void* __restrict__ g1,
    const void* __restrict__ b1,
    const void* __restrict__ wq, const void* __restrict__ bq,
    const void* __restrict__ wk, const void* __restrict__ bk,
    const void* __restrict__ wv, const void* __restrict__ bv,
    const int* __restrict__ dflag,
    unsigned* __restrict__ wpk, float* __restrict__ bpk,
    __half* __restrict__ x1)
{
  const int tid = threadIdx.x, lane = tid & 63, wid = tid >> 6;
  const int bf = *dflag;
  // ---- QKV weight/bias pre-pack for k_attn13 (blocks 0-4 only) ----
  if (blockIdx.x < 4) {
    for (int idx = blockIdx.x * 256 + tid; idx < 3 * 32 * 64; idx += 1024) {
      int m = idx >> 11;            // 0..2 (2048 words per matrix)
      int r = idx & 2047;
      int kp = r >> 6, col = r & 63;
      const void* ws = (m == 0) ? wq : (m == 1) ? wk : wv;
      wpk[idx] = packh2(ldf(ws, (2 * kp) * HD + col, bf),
                        ldf(ws, (2 * kp + 1) * HD + col, bf));
    }
  } else if (blockIdx.x == 4 && tid < 192) {
    int m = tid >> 6, col = tid & 63;
    const void* bs = (m == 0) ? bq : (m == 1) ? bk : bv;
    bpk[tid] = ldf(bs, col, bf);
  }
  const int n = blockIdx.x * 4 + wid;
  const float adn = ad_[n];
  float e0 = as_[n] + adn;
  e0 = e0 > 0.f ? e0 : 0.2f * e0;
  float den = __expf(fminf(e0, 30.f));
  float num = den * b2f(h[n * HD + lane]);
  const int deg = min(cur[n], DEGMAX);
  const int* row = ell + n * DEGMAX;
  int i = 0;
  for (; i + 8 <= deg; i += 8) {
    int s[8];
#pragma unroll
    for (int k = 0; k < 8; ++k) s[k] = row[i + k];
    float a[8], hh[8];
#pragma unroll
    for (int k = 0; k < 8; ++k) a[k] = as_[s[k]];
#pragma unroll
    for (int k = 0; k < 8; ++k) hh[k] = b2f(h[s[k] * HD + lane]);
#pragma unroll
    for (int k = 0; k < 8; ++k) {
      float e = a[k] + adn;
      e = e > 0.f ? e : 0.2f * e;
      float p = __expf(fminf(e, 30.f));
      den += p;
      num = fmaf(p, hh[k], num);
    }
  }
  for (; i + 4 <= deg; i += 4) {
    int s0 = row[i], s1 = row[i + 1], s2 = row[i + 2], s3 = row[i + 3];
    float a0 = as_[s0], a1 = as_[s1], a2 = as_[s2], a3 = as_[s3];
    float h0 = b2f(h[s0 * HD + lane]), h1 = b2f(h[s1 * HD + lane]);
    float h2 = b2f(h[s2 * HD + lane]), h3 = b2f(h[s3 * HD + lane]);
    float e_0 = a0 + adn; e_0 = e_0 > 0.f ? e_0 : 0.2f * e_0;
    float e_1 = a1 + adn; e_1 = e_1 > 0.f ? e_1 : 0.2f * e_1;
    float e_2 = a2 + adn; e_2 = e_2 > 0.f ? e_2 : 0.2f * e_2;
    float e_3 = a3 + adn; e_3 = e_3 > 0.f ? e_3 : 0.2f * e_3;
    float p0 = __expf(fminf(e_0, 30.f)), p1 = __expf(fminf(e_1, 30.f));
    float p2 = __expf(fminf(e_2, 30.f)), p3 = __expf(fminf(e_3, 30.f));
    den += p0 + p1 + p2 + p3;
    num = fmaf(p0, h0, num); num = fmaf(p1, h1, num);
    num = fmaf(p2, h2, num); num = fmaf(p3, h3, num);
  }
  for (; i < deg; ++i) {
    int s = row[i];
    float e = as_[s] + adn;
    e = e > 0.f ? e : 0.2f * e;
    float p = __expf(fminf(e, 30.f));
    den += p;
    num = fmaf(p, b2f(h[s * HD + lane]), num);
  }
  float v = num / (den + 1e-16f) + ldf(bg, lane, bf);
  v = fmaxf(v, 0.f) + ldf(x, n * HD + lane, bf);
  float mu = wave_sum(v) * (1.f / 64.f);
  float dv = v - mu;
  float var = wave_sum(dv * dv) * (1.f / 64.f);
  float r = rsqrtf(var + 1e-5f);
  x1[n * HD + lane] =
      __float2half(dv * r * ldf(g1, lane, bf) + ldf(b1, lane, bf));
}

// Kernel 3: fused QKV + dense attention, 512 threads, MFMA core.
// R31 structure, frozen this round.
__global__ __launch_bounds__(512, 2) void k_attn13(
    const __half* __restrict__ x1,
    const unsigned* __restrict__ wpk, const float* __restrict__ bpk,
    bf16* __restrict__ num_t, float* __restrict__ den_t)
{
  const int t = threadIdx.x;
  __shared__ _Float16 Qs[NPG * QS_STR];   // 12 KB
  __shared__ _Float16 Ks[256 * KS_STR];   // 6 KB
  __shared__ _Float16 Vt[DH * VT_STR];    // 4.1 KB (V transposed)
  const int bid = blockIdx.x;
  const int g = bid >> 4, hd = (bid >> 1) & 7, half = bid & 1;
  // qscale = (1/sqrt(8)) * log2(e): softmax via exp2 (folded into Q).
  const float qscale = 0.3535533905932738f * 1.4426950408889634f;
  {
    // ---- K (waves 0-3) or V (waves 4-7) projection for local row t&255 ----
    const int r = t & 255;
    const int m = (t < 256) ? 1 : 2;   // wave-uniform: no divergence
    const uint4* xk4 = (const uint4*)(x1 + (size_t)(g * NPG + half * 256 + r) * HD);
    const unsigned* wb0 = wpk + m * 2048 + hd * 8;   // uniform base
    float acc[DH];
#pragma unroll
    for (int j = 0; j < DH; ++j) acc[j] = bpk[m * 64 + hd * 8 + j];
#pragma unroll
    for (int blk = 0; blk < 8; ++blk) {
      uint4 xp = xk4[blk];             // 8 f16 of x row (4 pairs)
      const unsigned* wb = wb0 + blk * 256;   // kp = blk*4 .. +3
#pragma unroll
      for (int j = 0; j < DH; ++j) {
        acc[j] = fdot2u(xp.x, wb[j], acc[j]);
        acc[j] = fdot2u(xp.y, wb[64 + j], acc[j]);
        acc[j] = fdot2u(xp.z, wb[128 + j], acc[j]);
        acc[j] = fdot2u(xp.w, wb[192 + j], acc[j]);
      }
    }
    if (t < 256) {
      // K row r: 8 f16 packed, two 8B stores (24B row stride).
      unsigned w0 = packh2(acc[0], acc[1]), w1 = packh2(acc[2], acc[3]);
      unsigned w2 = packh2(acc[4], acc[5]), w3 = packh2(acc[6], acc[7]);
      *(uint2*)(Ks + r * KS_STR) = make_uint2(w0, w1);
      *(uint2*)(Ks + r * KS_STR + 4) = make_uint2(w2, w3);
    } else {
      // V row r transposed: 8 scalar f16 stores (2 lanes/bank = free).
#pragma unroll
      for (int j = 0; j < DH; ++j) Vt[j * VT_STR + r] = (_Float16)acc[j];
    }
  }
  {
    // ---- Q projection: row t -> Qs (pre-scaled by qscale) ----
    const uint4* xa4 = (const uint4*)(x1 + (size_t)(g * NPG + t) * HD);
    const unsigned* wb0 = wpk + hd * 8;              // m = 0
    float qa[DH];
#pragma unroll
    for (int j = 0; j < DH; ++j) qa[j] = bpk[hd * 8 + j];
#pragma unroll
    for (int blk = 0; blk < 8; ++blk) {
      uint4 xp = xa4[blk];
      const unsigned* wb = wb0 + blk * 256;
#pragma unroll
      for (int j = 0; j < DH; ++j) {
        qa[j] = fdot2u(xp.x, wb[j], qa[j]);
        qa[j] = fdot2u(xp.y, wb[64 + j], qa[j]);
        qa[j] = fdot2u(xp.z, wb[128 + j], qa[j]);
        qa[j] = fdot2u(xp.w, wb[192 + j], qa[j]);
      }
    }
    unsigned w0 = packh2(qa[0] * qscale, qa[1] * qscale);
    unsigned w1 = packh2(qa[2] * qscale, qa[3] * qscale);
    unsigned w2 = packh2(qa[4] * qscale, qa[5] * qscale);
    unsigned w3 = packh2(qa[6] * qscale, qa[7] * qscale);
    *(uint2*)(Qs + t * QS_STR) = make_uint2(w0, w1);
    *(uint2*)(Qs + t * QS_STR + 4) = make_uint2(w2, w3);
  }
  __syncthreads();   // Qs/Ks/Vt ready
  // ---- MFMA attention: 8 waves x 2 query-tiles of 32 (R30 verbatim) ----
  const int lane = t & 63, wid = t >> 6;
  const int ln = lane & 31, hh = lane >> 5;
  const int plane = half * 8 + hd;
  const size_t obase = (size_t)plane * NN + (size_t)g * NPG;
  v16f zf;
#pragma unroll
  for (int i = 0; i < 16; ++i) zf[i] = 0.f;
#pragma unroll
  for (int qt = 0; qt < 2; ++qt) {
    const int qbase = (wid * 2 + qt) * 32;
    // B-fragment: Q^T -> lane ln holds query qbase+ln, dh 4*hh..+3.
    v4h qf = *(const v4h*)(Qs + (qbase + ln) * QS_STR + 4 * hh);
    v16f oacc = zf;
    float den = 0.f;
#pragma unroll
    for (int kt = 0; kt < 8; ++kt) {
      // A-fragment: K -> lane ln holds key kt*32+ln, dh 4*hh..+3.
      v4h kf = *(const v4h*)(Ks + (kt * 32 + ln) * KS_STR + 4 * hh);
      v16f s = __builtin_amdgcn_mfma_f32_32x32x8f16(kf, qf, zf, 0, 0, 0);
#pragma unroll
      for (int g2 = 0; g2 < 4; ++g2) {
        float e0 = EXP2F(s[4 * g2 + 0]);
        float e1 = EXP2F(s[4 * g2 + 1]);
        float e2 = EXP2F(s[4 * g2 + 2]);
        float e3 = EXP2F(s[4 * g2 + 3]);
        den += (e0 + e1) + (e2 + e3);
        union { unsigned u[2]; v4h v; } pu;
        pu.u[0] = packh2(e0, e1);
        pu.u[1] = packh2(e2, e3);
        // B-fragment: V -> lane ln holds dh col ln&7 (cols 8-31 dup,
        // outputs there unread), keys kt*32+g2*8+4*hh..+3.
        v4h vf = *(const v4h*)(Vt + (ln & 7) * VT_STR + kt * 32 + g2 * 8 + 4 * hh);
        oacc = __builtin_amdgcn_mfma_f32_32x32x8f16(pu.v, vf, oacc, 0, 0, 0);
      }
    }
    // den: lane halves hold complementary key sets of the same query.
    den += __shfl_xor(den, 32);
    if (lane < 32) den_t[obase + qbase + lane] = den;
    // O: C layout -> lane ln<8 holds dh=ln; query per reg & lane-half.
#pragma unroll
    for (int r = 0; r < 16; ++r) {
      const int q = qbase + (r & 3) + 8 * (r >> 2) + 4 * hh;
      if (ln < 8)
        num_t[(obase + q) * 8 + ln] = __float2bfloat16(oacc[r]);
    }
  }
}

// Kernel 4: merge attn halves -> o; y = relu(o @ wo + bo); out = LN(x1+y).
// R32 MFMA structure, frozen this round.
__global__ __launch_bounds__(64) void k_out(
    const bf16* __restrict__ num_t, const float* __restrict__ den_t,
    const __half* __restrict__ x1,
    const void* __restrict__ wo, const void* __restrict__ bo,
    const void* __restrict__ g2, const void* __restrict__ b2,
    const int* __restrict__ dflag, void* __restrict__ out)
{
  const int t = threadIdx.x;
  const int bf = *dflag;
  const int ln = t & 31, hh = t >> 5;
  const int base = blockIdx.x * 32;
  const int n = base + ln;
  v16f c0, c1;
#pragma unroll
  for (int i = 0; i < 16; ++i) { c0[i] = 0.f; c1[i] = 0.f; }
#pragma unroll
  for (int kt = 0; kt < 8; ++kt) {
    // A-frag: o[node n][dims kt*8+4hh .. +3] = (num_lo+num_hi)/den
    union { uint2 u; unsigned short s[4]; } L, H;
    L.u = *(const uint2*)(num_t + ((size_t)kt * NN + n) * 8 + 4 * hh);
    H.u = *(const uint2*)(num_t + ((size_t)(8 + kt) * NN + n) * 8 + 4 * hh);
    float den = den_t[(size_t)kt * NN + n] + den_t[(size_t)(8 + kt) * NN + n];
    float rden = 1.f / den;
    float o0 = (__uint_as_float((unsigned)L.s[0] << 16) +
                __uint_as_float((unsigned)H.s[0] << 16)) * rden;
    float o1 = (__uint_as_float((unsigned)L.s[1] << 16) +
                __uint_as_float((unsigned)H.s[1] << 16)) * rden;
    float o2 = (__uint_as_float((unsigned)L.s[2] << 16) +
                __uint_as_float((unsigned)H.s[2] << 16)) * rden;
    float o3 = (__uint_as_float((unsigned)L.s[3] << 16) +
                __uint_as_float((unsigned)H.s[3] << 16)) * rden;
    union { unsigned u[2]; v4h v; } A;
    A.u[0] = packh2(o0, o1);
    A.u[1] = packh2(o2, o3);
    // B-frags: wo rows kt*8+4hh..+3, cols ln (ct=0) and 32+ln (ct=1).
    const int kr = kt * 8 + 4 * hh;
    union { unsigned u[2]; v4h v; } B0, B1;
    B0.u[0] = packh2(ldf(wo, (kr + 0) * HD + ln, bf),
                     ldf(wo, (kr + 1) * HD + ln, bf));
    B0.u[1] = packh2(ldf(wo, (kr + 2) * HD + ln, bf),
                     ldf(wo, (kr + 3) * HD + ln, bf));
    B1.u[0] = packh2(ldf(wo, (kr + 0) * HD + 32 + ln, bf),
                     ldf(wo, (kr + 1) * HD + 32 + ln, bf));
    B1.u[1] = packh2(ldf(wo, (kr + 2) * HD + 32 + ln, bf),
                     ldf(wo, (kr + 3) * HD + 32 + ln, bf));
    c0 = __builtin_amdgcn_mfma_f32_32x32x8f16(A.v, B0.v, c0, 0, 0, 0);
    c1 = __builtin_amdgcn_mfma_f32_32x32x8f16(A.v, B1.v, c1, 0, 0, 0);
  }
  // Epilogue: bias+relu+residual+LN per C row (row fully in one 32-half).
  const float bo0 = ldf(bo, ln, bf),      bo1 = ldf(bo, 32 + ln, bf);
  const float g20 = ldf(g2, ln, bf),      g21 = ldf(g2, 32 + ln, bf);
  const float b20 = ldf(b2, ln, bf),      b21 = ldf(b2, 32 + ln, bf);
#pragma unroll
  for (int r = 0; r < 16; ++r) {
    const int node = base + (r & 3) + 8 * (r >> 2) + 4 * hh;
    float t0 = __half2float(x1[node * HD + ln]) + fmaxf(c0[r] + bo0, 0.f);
    float t1 = __half2float(x1[node * HD + 32 + ln]) + fmaxf(c1[r] + bo1, 0.f);
    float s = t0 + t1;
#pragma unroll
    for (int off = 1; off < 32; off <<= 1) s += __shfl_xor(s, off);
    const float mu = s * (1.f / 64.f);
    const float d0 = t0 - mu, d1 = t1 - mu;
    float v = d0 * d0 + d1 * d1;
#pragma unroll
    for (int off = 1; off < 32; off <<= 1) v += __shfl_xor(v, off);
    const float rr = rsqrtf(v * (1.f / 64.f) + 1e-5f);
    const float r0 = d0 * rr * g20 + b20;
    const float r1 = d1 * rr * g21 + b21;
    if (bf) {
      ((bf16*)out)[node * HD + ln]      = __float2bfloat16(r0);
      ((bf16*)out)[node * HD + 32 + ln] = __float2bfloat16(r1);
    } else {
      ((float*)out)[node * HD + ln]      = r0;
      ((float*)out)[node * HD + 32 + ln] = r1;
    }
  }
}

extern "C" void kernel_launch(void* const* d_in, const int* in_sizes, int n_in,
                              void* d_out, int out_size, void* d_ws, size_t ws_size,
                              hipStream_t stream)
{
  const void* x    = d_in[0];
  const void* wgat = d_in[1];
  const void* asrc = d_in[2];
  const void* adst = d_in[3];
  const void* bgat = d_in[4];
  const void* g1   = d_in[5];
  const void* b1   = d_in[6];
  const void* wq   = d_in[7];
  const void* bq   = d_in[8];
  const void* wk   = d_in[9];
  const void* bk   = d_in[10];
  const void* wv   = d_in[11];
  const void* bv   = d_in[12];
  const void* wo   = d_in[13];
  const void* bo   = d_in[14];
  const void* g2   = d_in[15];
  const void* b2   = d_in[16];
  const int*  ei   = (const int*)d_in[17];
  const int E = in_sizes[17] / 2;
  const int* esrc = ei;
  const int* edst = ei + E;

  // Workspace (~7.3 MiB):
  //   [0, 2M):      f16 x1
  //   [2M, 4.62M):  ell (NN*DEGMAX int)    } dead after k_gather;
  //   [4.62M,6.62M):bf16 h                 } k_attn13 overwrites:
  //   [2M, 6M):     bf16 num_t (16 planes * NN * 8)
  //   [6M, 7M):     f32 den_t (16 planes * NN)
  //   [7M, ...):    as_, ad_ (NN f32 each), cur (NN int), flag,
  //                 wpk (6144 u32), bpk (192 f32)
  char* W = (char*)d_ws;
  __half* x1b  = (__half*)W;
  int*   ell   = (int*)(W + (size_t)(2 << 20));
  bf16*  hb    = (bf16*)(W + (size_t)(2 << 20) + (size_t)NN * DEGMAX * 4);
  bf16*  num_t = (bf16*)(W + (size_t)(2 << 20));
  float* den_t = (float*)(W + (size_t)(6 << 20));
  float* as_   = (float*)(W + (size_t)(7 << 20));
  float* ad_   = as_ + NN;
  int*   cur   = (int*)(ad_ + NN);
  int*   flag  = cur + NN;
  unsigned* wpk = (unsigned*)(flag + 1);
  float* bpk   = (float*)(wpk + 3 * 32 * 64);

  hipMemsetAsync(cur, 0, NN * sizeof(int), stream);
  k_build  <<<NN / 32, 64, 0, stream>>>(x, wgat, asrc, adst, esrc, edst, E,
                                        cur, ell, hb, as_, ad_, flag);
  k_gather <<<NN / 4, 256, 0, stream>>>(x, cur, ell, as_, ad_, hb,
                                        bgat, g1, b1,
                                        wq, bq, wk, bk, wv, bv,
                                        flag, wpk, bpk, x1b);
  k_attn13 <<<BG * NHEADS * 2, 512, 0, stream>>>(x1b, wpk, bpk, num_t, den_t);
  k_out    <<<NN / 32, 64, 0, stream>>>(num_t, den_t, x1b, wo, bo, g2, b2,
                                        flag, d_out);
}

// Round 15
// 171.562 us; speedup vs baseline: 1.0495x; 1.0123x over previous
//
#include <hip/hip_runtime.h>
#include <hip/hip_bf16.h>
#include <hip/hip_fp16.h>

// Problem constants (from reference)
#define NN     16384   // nodes
#define HD     64      // hidden dim
#define BG     32      // graphs
#define NPG    512     // nodes per graph
#define NHEADS 8
#define DH     8
#define DEGMAX 40      // ELL width; deg ~ Poisson(16), P(>40) ~ 3e-8/node

// R30 MFMA attn LDS geometry (f16):
//   Qs[512][12], Ks[256][12]: row stride 12 f16 = 24B -> b64 fragment reads
//   8B-aligned; bank stride 6 -> only 2-way aliasing (free, m136).
//   Vt[8][264]: V transposed; row stride 528B -> conflict-free b64 frags.
#define QS_STR 12
#define KS_STR 12
#define VT_STR 264

typedef __hip_bfloat16 bf16;
typedef _Float16 v4h __attribute__((ext_vector_type(4)));
typedef float v16f __attribute__((ext_vector_type(16)));

#if defined(__has_builtin)
#if __has_builtin(__builtin_amdgcn_exp2f)
#define EXP2F(x) __builtin_amdgcn_exp2f(x)
#else
#define EXP2F(x) exp2f(x)
#endif
#if __has_builtin(__builtin_amdgcn_fdot2)
#define HAS_FDOT2 1
#endif
#else
#define EXP2F(x) exp2f(x)
#endif

#ifdef HAS_FDOT2
typedef _Float16 hvec2 __attribute__((ext_vector_type(2)));
#endif

// dot2 on two packed-f16 u32 words, f32 accumulate (fallback: plain f32).
__device__ __forceinline__ float fdot2u(unsigned a, unsigned b, float c) {
#ifdef HAS_FDOT2
  union { unsigned u; hvec2 v; } x, y;
  x.u = a; y.u = b;
  return __builtin_amdgcn_fdot2(x.v, y.v, c, false);
#else
  union { unsigned u; __half2 h; } x, y;
  x.u = a; y.u = b;
  return fmaf(__low2float(x.h), __low2float(y.h),
              fmaf(__high2float(x.h), __high2float(y.h), c));
#endif
}

__device__ __forceinline__ float b2f(bf16 v) { return __bfloat162float(v); }

// Flag-steered input load: bf=1 -> buffer is bf16, bf=0 -> fp32.
__device__ __forceinline__ float ldf(const void* p, int i, int bf) {
  return bf ? __bfloat162float(((const bf16*)p)[i]) : ((const float*)p)[i];
}

__device__ __forceinline__ float wave_sum(float v) {
#pragma unroll
  for (int off = 32; off > 0; off >>= 1) v += __shfl_xor(v, off);
  return v;
}

__device__ __forceinline__ unsigned packh2(float a, float b) {
  union { unsigned u; __half2 h; } z;
  z.h = __floats2half2_rn(a, b);
  return z.u;
}

// Per-block dtype detection (bf16 vs fp32 inputs); 256 exponent samples.
__device__ __forceinline__ int detect_bf(const unsigned short* xr, int tid, int nt) {
  __shared__ int s_cnt;
  if (tid == 0) s_cnt = 0;
  __syncthreads();
  int sane = 0;
  for (int i = tid; i < 256; i += nt) {
    int e = (xr[2 * i] >> 7) & 0xFF;
    sane += (e >= 100 && e <= 150) ? 1 : 0;
  }
  if (sane) atomicAdd(&s_cnt, sane);
  __syncthreads();
  return s_cnt > 180;
}

// Kernel 0 (R34, replaces hipMemsetAsync): zero cur + publish dtype flag +
// pre-pack w_gat/wo into MFMA B-fragment order. Entry e of wgp/wop =
// (kt,hh,ct,ln): uint2{packh2(w[kr][col],w[kr+1][col]),
// packh2(w[kr+2][col],w[kr+3][col])}, kr=kt*8+4hh, col=ct*32+ln ->
// k_build/k_out read B-frags as ONE coalesced uint2 instead of 16 scalar
// bf16 loads (Common-mistake #2, applied to global this time).
__global__ __launch_bounds__(256) void k_prep(
    const void* __restrict__ x, const void* __restrict__ w,
    const void* __restrict__ wo,
    int* __restrict__ cur, uint2* __restrict__ wgp, uint2* __restrict__ wop,
    int* __restrict__ flagp)
{
  const int tid = threadIdx.x, b = blockIdx.x;
  if (b < 64) {                      // zero cur (64 x 256 = NN)
    cur[b * 256 + tid] = 0;
    return;
  }
  const int bf = detect_bf((const unsigned short*)x, tid, 256);
  if (b == 64 && tid == 0) *flagp = bf;
  const void* src = (b == 64) ? w : wo;
  uint2* dst = (b == 64) ? wgp : wop;
  for (int e = tid; e < 1024; e += 256) {
    const int ln = e & 31, ct = (e >> 5) & 1, hh = (e >> 6) & 1, kt = e >> 7;
    const int kr = kt * 8 + 4 * hh, col = ct * 32 + ln;
    uint2 v;
    v.x = packh2(ldf(src, (kr + 0) * HD + col, bf),
                 ldf(src, (kr + 1) * HD + col, bf));
    v.y = packh2(ldf(src, (kr + 2) * HD + col, bf),
                 ldf(src, (kr + 3) * HD + col, bf));
    dst[e] = v;
  }
}

// Kernel 1: h = x @ w_gat + as_/ad_ + fused ELL scatter. R33 MFMA shape;
// R34: A-frags via one vector load (uint2 bf16 / float4 f32, branch is
// wave-uniform); B-frags via 2 coalesced uint2 from wgp. 160 -> 24
// loads/thread (at 2 waves/CU every chain was latency-exposed).
__global__ __launch_bounds__(64) void k_build(
    const void* __restrict__ x, const uint2* __restrict__ wgp,
    const void* __restrict__ asrc, const void* __restrict__ adst,
    const int* __restrict__ esrc, const int* __restrict__ edst, int E,
    int* __restrict__ cur, int* __restrict__ ell,
    bf16* __restrict__ h, float* __restrict__ as_, float* __restrict__ ad_,
    const int* __restrict__ dflag)
{
  const int t = threadIdx.x;          // 0..63, one wave
  const int ln = t & 31, hh = t >> 5;
  const int bf = *dflag;
  // ---- edge scatter: 8 grid-stride iterations ----
  for (int e = blockIdx.x * 64 + t; e < E; e += gridDim.x * 64) {
    int d = edst[e];
    int k = atomicAdd(&cur[d], 1);
    if (k < DEGMAX) ell[d * DEGMAX + k] = esrc[e];
  }
  // ---- MFMA: h[base..base+31][0:64] = x-rows @ w ----
  const int base = blockIdx.x * 32;
  v16f c0, c1;
#pragma unroll
  for (int i = 0; i < 16; ++i) { c0[i] = 0.f; c1[i] = 0.f; }
#pragma unroll
  for (int kt = 0; kt < 8; ++kt) {
    const int kr = kt * 8 + 4 * hh;
    union { unsigned u[2]; v4h v; } A, B0, B1;
    if (bf) {
      uint2 xv = *(const uint2*)((const unsigned short*)x +
                                 (size_t)(base + ln) * HD + kr);
      A.u[0] = packh2(__uint_as_float(xv.x << 16),
                      __uint_as_float(xv.x & 0xffff0000u));
      A.u[1] = packh2(__uint_as_float(xv.y << 16),
                      __uint_as_float(xv.y & 0xffff0000u));
    } else {
      float4 xv = *(const float4*)((const float*)x +
                                   (size_t)(base + ln) * HD + kr);
      A.u[0] = packh2(xv.x, xv.y);
      A.u[1] = packh2(xv.z, xv.w);
    }
    uint2 b0 = wgp[((kt * 2 + hh) * 2 + 0) * 32 + ln];
    uint2 b1 = wgp[((kt * 2 + hh) * 2 + 1) * 32 + ln];
    B0.u[0] = b0.x; B0.u[1] = b0.y;
    B1.u[0] = b1.x; B1.u[1] = b1.y;
    c0 = __builtin_amdgcn_mfma_f32_32x32x8f16(A.v, B0.v, c0, 0, 0, 0);
    c1 = __builtin_amdgcn_mfma_f32_32x32x8f16(A.v, B1.v, c1, 0, 0, 0);
  }
  // ---- epilogue: store h (bf16); as_/ad_ via 32-half reductions ----
  const float av0 = ldf(asrc, ln, bf), av1 = ldf(asrc, 32 + ln, bf);
  const float dv0 = ldf(adst, ln, bf), dv1 = ldf(adst, 32 + ln, bf);
#pragma unroll
  for (int r = 0; r < 16; ++r) {
    const int node = base + (r & 3) + 8 * (r >> 2) + 4 * hh;
    h[node * HD + ln]      = __float2bfloat16(c0[r]);
    h[node * HD + 32 + ln] = __float2bfloat16(c1[r]);
    float pa = c0[r] * av0 + c1[r] * av1;
    float pd = c0[r] * dv0 + c1[r] * dv1;
#pragma unroll
    for (int off = 16; off > 0; off >>= 1) {
      pa += __shfl_xor(pa, off);
      pd += __shfl_xor(pd, off);
    }
    if (ln == 0) { as_[node] = pa; ad_[node] = pd; }
  }
}

// Kernel 2: wave-per-node GAT gather (ELL) + bias + relu + residual + LN1 -> x1
// R31: x1 stored f16; blocks 0-4 pre-pack [Wq|Wk|Wv]/biases for k_attn13.
// Frozen.
__global__ __launch_bounds__(256) void k_gather(
    const void* __restrict__ x, const int* __restrict__ cur,
    const int* __restrict__ ell, const float* __restrict__ as_,
    const float* __restrict__ ad_, const bf16* __restrict__ h,
    const void* __restrict__ bg, const void* __restrict__ g1,
    const void* __restrict__ b1,
    const void* __restrict__ wq, const void* __restrict__ bq,
    const void* __restrict__ wk, const void* __restrict__ bk,
    const void* __restrict__ wv, const void* __restrict__ bv,
    const int* __restrict__ dflag,
    unsigned* __restrict__ wpk, float* __restrict__ bpk,
    __half* __restrict__ x1)
{
  const int tid = threadIdx.x, lane = tid & 63, wid = tid >> 6;
  const int bf = *dflag;
  // ---- QKV weight/bias pre-pack for k_attn13 (blocks 0-4 only) ----
  if (blockIdx.x < 4) {
    for (int idx = blockIdx.x * 256 + tid; idx < 3 * 32 * 64; idx += 1024) {
      int m = idx >> 11;            // 0..2 (2048 words per matrix)
      int r = idx & 2047;
      int kp = r >> 6, col = r & 63;
      const void* ws = (m == 0) ? wq : (m == 1) ? wk : wv;
      wpk[idx] = packh2(ldf(ws, (2 * kp) * HD + col, bf),
                        ldf(ws, (2 * kp + 1) * HD + col, bf));
    }
  } else if (blockIdx.x == 4 && tid < 192) {
    int m = tid >> 6, col = tid & 63;
    const void* bs = (m == 0) ? bq : (m == 1) ? bk : bv;
    bpk[tid] = ldf(bs, col, bf);
  }
  const int n = blockIdx.x * 4 + wid;
  const float adn = ad_[n];
  float e0 = as_[n] + adn;
  e0 = e0 > 0.f ? e0 : 0.2f * e0;
  float den = __expf(fminf(e0, 30.f));
  float num = den * b2f(h[n * HD + lane]);
  const int deg = min(cur[n], DEGMAX);
  const int* row = ell + n * DEGMAX;
  int i = 0;
  for (; i + 8 <= deg; i += 8) {
    int s[8];
#pragma unroll
    for (int k = 0; k < 8; ++k) s[k] = row[i + k];
    float a[8], hh[8];
#pragma unroll
    for (int k = 0; k < 8; ++k) a[k] = as_[s[k]];
#pragma unroll
    for (int k = 0; k < 8; ++k) hh[k] = b2f(h[s[k] * HD + lane]);
#pragma unroll
    for (int k = 0; k < 8; ++k) {
      float e = a[k] + adn;
      e = e > 0.f ? e : 0.2f * e;
      float p = __expf(fminf(e, 30.f));
      den += p;
      num = fmaf(p, hh[k], num);
    }
  }
  for (; i + 4 <= deg; i += 4) {
    int s0 = row[i], s1 = row[i + 1], s2 = row[i + 2], s3 = row[i + 3];
    float a0 = as_[s0], a1 = as_[s1], a2 = as_[s2], a3 = as_[s3];
    float h0 = b2f(h[s0 * HD + lane]), h1 = b2f(h[s1 * HD + lane]);
    float h2 = b2f(h[s2 * HD + lane]), h3 = b2f(h[s3 * HD + lane]);
    float e_0 = a0 + adn; e_0 = e_0 > 0.f ? e_0 : 0.2f * e_0;
    float e_1 = a1 + adn; e_1 = e_1 > 0.f ? e_1 : 0.2f * e_1;
    float e_2 = a2 + adn; e_2 = e_2 > 0.f ? e_2 : 0.2f * e_2;
    float e_3 = a3 + adn; e_3 = e_3 > 0.f ? e_3 : 0.2f * e_3;
    float p0 = __expf(fminf(e_0, 30.f)), p1 = __expf(fminf(e_1, 30.f));
    float p2 = __expf(fminf(e_2, 30.f)), p3 = __expf(fminf(e_3, 30.f));
    den += p0 + p1 + p2 + p3;
    num = fmaf(p0, h0, num); num = fmaf(p1, h1, num);
    num = fmaf(p2, h2, num); num = fmaf(p3, h3, num);
  }
  for (; i < deg; ++i) {
    int s = row[i];
    float e = as_[s] + adn;
    e = e > 0.f ? e : 0.2f * e;
    float p = __expf(fminf(e, 30.f));
    den += p;
    num = fmaf(p, b2f(h[s * HD + lane]), num);
  }
  float v = num / (den + 1e-16f) + ldf(bg, lane, bf);
  v = fmaxf(v, 0.f) + ldf(x, n * HD + lane, bf);
  float mu = wave_sum(v) * (1.f / 64.f);
  float dv = v - mu;
  float var = wave_sum(dv * dv) * (1.f / 64.f);
  float r = rsqrtf(var + 1e-5f);
  x1[n * HD + lane] =
      __float2half(dv * r * ldf(g1, lane, bf) + ldf(b1, lane, bf));
}

// Kernel 3: fused QKV + dense attention, 512 threads, MFMA core.
// R31 structure, frozen.
__global__ __launch_bounds__(512, 2) void k_attn13(
    const __half* __restrict__ x1,
    const unsigned* __restrict__ wpk, const float* __restrict__ bpk,
    bf16* __restrict__ num_t, float* __restrict__ den_t)
{
  const int t = threadIdx.x;
  __shared__ _Float16 Qs[NPG * QS_STR];   // 12 KB
  __shared__ _Float16 Ks[256 * KS_STR];   // 6 KB
  __shared__ _Float16 Vt[DH * VT_STR];    // 4.1 KB (V transposed)
  const int bid = blockIdx.x;
  const int g = bid >> 4, hd = (bid >> 1) & 7, half = bid & 1;
  // qscale = (1/sqrt(8)) * log2(e): softmax via exp2 (folded into Q).
  const float qscale = 0.3535533905932738f * 1.4426950408889634f;
  {
    // ---- K (waves 0-3) or V (waves 4-7) projection for local row t&255 ----
    const int r = t & 255;
    const int m = (t < 256) ? 1 : 2;   // wave-uniform: no divergence
    const uint4* xk4 = (const uint4*)(x1 + (size_t)(g * NPG + half * 256 + r) * HD);
    const unsigned* wb0 = wpk + m * 2048 + hd * 8;   // uniform base
    float acc[DH];
#pragma unroll
    for (int j = 0; j < DH; ++j) acc[j] = bpk[m * 64 + hd * 8 + j];
#pragma unroll
    for (int blk = 0; blk < 8; ++blk) {
      uint4 xp = xk4[blk];             // 8 f16 of x row (4 pairs)
      const unsigned* wb = wb0 + blk * 256;   // kp = blk*4 .. +3
#pragma unroll
      for (int j = 0; j < DH; ++j) {
        acc[j] = fdot2u(xp.x, wb[j], acc[j]);
        acc[j] = fdot2u(xp.y, wb[64 + j], acc[j]);
        acc[j] = fdot2u(xp.z, wb[128 + j], acc[j]);
        acc[j] = fdot2u(xp.w, wb[192 + j], acc[j]);
      }
    }
    if (t < 256) {
      // K row r: 8 f16 packed, two 8B stores (24B row stride).
      unsigned w0 = packh2(acc[0], acc[1]), w1 = packh2(acc[2], acc[3]);
      unsigned w2 = packh2(acc[4], acc[5]), w3 = packh2(acc[6], acc[7]);
      *(uint2*)(Ks + r * KS_STR) = make_uint2(w0, w1);
      *(uint2*)(Ks + r * KS_STR + 4) = make_uint2(w2, w3);
    } else {
      // V row r transposed: 8 scalar f16 stores (2 lanes/bank = free).
#pragma unroll
      for (int j = 0; j < DH; ++j) Vt[j * VT_STR + r] = (_Float16)acc[j];
    }
  }
  {
    // ---- Q projection: row t -> Qs (pre-scaled by qscale) ----
    const uint4* xa4 = (const uint4*)(x1 + (size_t)(g * NPG + t) * HD);
    const unsigned* wb0 = wpk + hd * 8;              // m = 0
    float qa[DH];
#pragma unroll
    for (int j = 0; j < DH; ++j) qa[j] = bpk[hd * 8 + j];
#pragma unroll
    for (int blk = 0; blk < 8; ++blk) {
      uint4 xp = xa4[blk];
      const unsigned* wb = wb0 + blk * 256;
#pragma unroll
      for (int j = 0; j < DH; ++j) {
        qa[j] = fdot2u(xp.x, wb[j], qa[j]);
        qa[j] = fdot2u(xp.y, wb[64 + j], qa[j]);
        qa[j] = fdot2u(xp.z, wb[128 + j], qa[j]);
        qa[j] = fdot2u(xp.w, wb[192 + j], qa[j]);
      }
    }
    unsigned w0 = packh2(qa[0] * qscale, qa[1] * qscale);
    unsigned w1 = packh2(qa[2] * qscale, qa[3] * qscale);
    unsigned w2 = packh2(qa[4] * qscale, qa[5] * qscale);
    unsigned w3 = packh2(qa[6] * qscale, qa[7] * qscale);
    *(uint2*)(Qs + t * QS_STR) = make_uint2(w0, w1);
    *(uint2*)(Qs + t * QS_STR + 4) = make_uint2(w2, w3);
  }
  __syncthreads();   // Qs/Ks/Vt ready
  // ---- MFMA attention: 8 waves x 2 query-tiles of 32 (R30 verbatim) ----
  const int lane = t & 63, wid = t >> 6;
  const int ln = lane & 31, hh = lane >> 5;
  const int plane = half * 8 + hd;
  const size_t obase = (size_t)plane * NN + (size_t)g * NPG;
  v16f zf;
#pragma unroll
  for (int i = 0; i < 16; ++i) zf[i] = 0.f;
#pragma unroll
  for (int qt = 0; qt < 2; ++qt) {
    const int qbase = (wid * 2 + qt) * 32;
    // B-fragment: Q^T -> lane ln holds query qbase+ln, dh 4*hh..+3.
    v4h qf = *(const v4h*)(Qs + (qbase + ln) * QS_STR + 4 * hh);
    v16f oacc = zf;
    float den = 0.f;
#pragma unroll
    for (int kt = 0; kt < 8; ++kt) {
      // A-fragment: K -> lane ln holds key kt*32+ln, dh 4*hh..+3.
      v4h kf = *(const v4h*)(Ks + (kt * 32 + ln) * KS_STR + 4 * hh);
      v16f s = __builtin_amdgcn_mfma_f32_32x32x8f16(kf, qf, zf, 0, 0, 0);
#pragma unroll
      for (int g2 = 0; g2 < 4; ++g2) {
        float e0 = EXP2F(s[4 * g2 + 0]);
        float e1 = EXP2F(s[4 * g2 + 1]);
        float e2 = EXP2F(s[4 * g2 + 2]);
        float e3 = EXP2F(s[4 * g2 + 3]);
        den += (e0 + e1) + (e2 + e3);
        union { unsigned u[2]; v4h v; } pu;
        pu.u[0] = packh2(e0, e1);
        pu.u[1] = packh2(e2, e3);
        // B-fragment: V -> lane ln holds dh col ln&7 (cols 8-31 dup,
        // outputs there unread), keys kt*32+g2*8+4*hh..+3.
        v4h vf = *(const v4h*)(Vt + (ln & 7) * VT_STR + kt * 32 + g2 * 8 + 4 * hh);
        oacc = __builtin_amdgcn_mfma_f32_32x32x8f16(pu.v, vf, oacc, 0, 0, 0);
      }
    }
    // den: lane halves hold complementary key sets of the same query.
    den += __shfl_xor(den, 32);
    if (lane < 32) den_t[obase + qbase + lane] = den;
    // O: C layout -> lane ln<8 holds dh=ln; query per reg & lane-half.
#pragma unroll
    for (int r = 0; r < 16; ++r) {
      const int q = qbase + (r & 3) + 8 * (r >> 2) + 4 * hh;
      if (ln < 8)
        num_t[(obase + q) * 8 + ln] = __float2bfloat16(oacc[r]);
    }
  }
}

// Kernel 4: merge attn halves -> o; y = relu(o @ wo + bo); out = LN(x1+y).
// R32 MFMA structure; R34: B-frags from pre-packed wop (2 coalesced uint2
// per kt instead of 16 scalar bf16 loads).
__global__ __launch_bounds__(64) void k_out(
    const bf16* __restrict__ num_t, const float* __restrict__ den_t,
    const __half* __restrict__ x1, const uint2* __restrict__ wop,
    const void* __restrict__ bo,
    const void* __restrict__ g2, const void* __restrict__ b2,
    const int* __restrict__ dflag, void* __restrict__ out)
{
  const int t = threadIdx.x;
  const int bf = *dflag;
  const int ln = t & 31, hh = t >> 5;
  const int base = blockIdx.x * 32;
  const int n = base + ln;
  v16f c0, c1;
#pragma unroll
  for (int i = 0; i < 16; ++i) { c0[i] = 0.f; c1[i] = 0.f; }
#pragma unroll
  for (int kt = 0; kt < 8; ++kt) {
    // A-frag: o[node n][dims kt*8+4hh .. +3] = (num_lo+num_hi)/den
    union { uint2 u; unsigned short s[4]; } L, H;
    L.u = *(const uint2*)(num_t + ((size_t)kt * NN + n) * 8 + 4 * hh);
    H.u = *(const uint2*)(num_t + ((size_t)(8 + kt) * NN + n) * 8 + 4 * hh);
    float den = den_t[(size_t)kt * NN + n] + den_t[(size_t)(8 + kt) * NN + n];
    float rden = 1.f / den;
    float o0 = (__uint_as_float((unsigned)L.s[0] << 16) +
                __uint_as_float((unsigned)H.s[0] << 16)) * rden;
    float o1 = (__uint_as_float((unsigned)L.s[1] << 16) +
                __uint_as_float((unsigned)H.s[1] << 16)) * rden;
    float o2 = (__uint_as_float((unsigned)L.s[2] << 16) +
                __uint_as_float((unsigned)H.s[2] << 16)) * rden;
    float o3 = (__uint_as_float((unsigned)L.s[3] << 16) +
                __uint_as_float((unsigned)H.s[3] << 16)) * rden;
    union { unsigned u[2]; v4h v; } A, B0, B1;
    A.u[0] = packh2(o0, o1);
    A.u[1] = packh2(o2, o3);
    uint2 b0 = wop[((kt * 2 + hh) * 2 + 0) * 32 + ln];
    uint2 b1 = wop[((kt * 2 + hh) * 2 + 1) * 32 + ln];
    B0.u[0] = b0.x; B0.u[1] = b0.y;
    B1.u[0] = b1.x; B1.u[1] = b1.y;
    c0 = __builtin_amdgcn_mfma_f32_32x32x8f16(A.v, B0.v, c0, 0, 0, 0);
    c1 = __builtin_amdgcn_mfma_f32_32x32x8f16(A.v, B1.v, c1, 0, 0, 0);
  }
  // Epilogue: bias+relu+residual+LN per C row (row fully in one 32-half).
  const float bo0 = ldf(bo, ln, bf),      bo1 = ldf(bo, 32 + ln, bf);
  const float g20 = ldf(g2, ln, bf),      g21 = ldf(g2, 32 + ln, bf);
  const float b20 = ldf(b2, ln, bf),      b21 = ldf(b2, 32 + ln, bf);
#pragma unroll
  for (int r = 0; r < 16; ++r) {
    const int node = base + (r & 3) + 8 * (r >> 2) + 4 * hh;
    float t0 = __half2float(x1[node * HD + ln]) + fmaxf(c0[r] + bo0, 0.f);
    float t1 = __half2float(x1[node * HD + 32 + ln]) + fmaxf(c1[r] + bo1, 0.f);
    float s = t0 + t1;
#pragma unroll
    for (int off = 1; off < 32; off <<= 1) s += __shfl_xor(s, off);
    const float mu = s * (1.f / 64.f);
    const float d0 = t0 - mu, d1 = t1 - mu;
    float v = d0 * d0 + d1 * d1;
#pragma unroll
    for (int off = 1; off < 32; off <<= 1) v += __shfl_xor(v, off);
    const float rr = rsqrtf(v * (1.f / 64.f) + 1e-5f);
    const float r0 = d0 * rr * g20 + b20;
    const float r1 = d1 * rr * g21 + b21;
    if (bf) {
      ((bf16*)out)[node * HD + ln]      = __float2bfloat16(r0);
      ((bf16*)out)[node * HD + 32 + ln] = __float2bfloat16(r1);
    } else {
      ((float*)out)[node * HD + ln]      = r0;
      ((float*)out)[node * HD + 32 + ln] = r1;
    }
  }
}

extern "C" void kernel_launch(void* const* d_in, const int* in_sizes, int n_in,
                              void* d_out, int out_size, void* d_ws, size_t ws_size,
                              hipStream_t stream)
{
  const void* x    = d_in[0];
  const void* wgat = d_in[1];
  const void* asrc = d_in[2];
  const void* adst = d_in[3];
  const void* bgat = d_in[4];
  const void* g1   = d_in[5];
  const void* b1   = d_in[6];
  const void* wq   = d_in[7];
  const void* bq   = d_in[8];
  const void* wk   = d_in[9];
  const void* bk   = d_in[10];
  const void* wv   = d_in[11];
  const void* bv   = d_in[12];
  const void* wo   = d_in[13];
  const void* bo   = d_in[14];
  const void* g2   = d_in[15];
  const void* b2   = d_in[16];
  const int*  ei   = (const int*)d_in[17];
  const int E = in_sizes[17] / 2;
  const int* esrc = ei;
  const int* edst = ei + E;

  // Workspace (~7.3 MiB):
  //   [0, 2M):      f16 x1
  //   [2M, 4.62M):  ell (NN*DEGMAX int)    } dead after k_gather;
  //   [4.62M,6.62M):bf16 h                 } k_attn13 overwrites:
  //   [2M, 6M):     bf16 num_t (16 planes * NN * 8)
  //   [6M, 7M):     f32 den_t (16 planes * NN)
  //   [7M, ...):    as_, ad_ (NN f32 each), cur (NN int), flag,
  //                 wpk (6144 u32), bpk (192 f32), wgp/wop (1024 uint2 ea)
  char* W = (char*)d_ws;
  __half* x1b  = (__half*)W;
  int*   ell   = (int*)(W + (size_t)(2 << 20));
  bf16*  hb    = (bf16*)(W + (size_t)(2 << 20) + (size_t)NN * DEGMAX * 4);
  bf16*  num_t = (bf16*)(W + (size_t)(2 << 20));
  float* den_t = (float*)(W + (size_t)(6 << 20));
  float* as_   = (float*)(W + (size_t)(7 << 20));
  float* ad_   = as_ + NN;
  int*   cur   = (int*)(ad_ + NN);
  int*   flag  = cur + NN;
  unsigned* wpk = (unsigned*)(flag + 1);
  float* bpk   = (float*)(wpk + 3 * 32 * 64);
  uint2* wgp   = (uint2*)(bpk + 192);
  uint2* wop   = wgp + 1024;

  k_prep   <<<66, 256, 0, stream>>>(x, wgat, wo, cur, wgp, wop, flag);
  k_build  <<<NN / 32, 64, 0, stream>>>(x, wgp, asrc, adst, esrc, edst, E,
                                        cur, ell, hb, as_, ad_, flag);
  k_gather <<<NN / 4, 256, 0, stream>>>(x, cur, ell, as_, ad_, hb,
                                        bgat, g1, b1,
                                        wq, bq, wk, bk, wv, bv,
                                        flag, wpk, bpk, x1b);
  k_attn13 <<<BG * NHEADS * 2, 512, 0, stream>>>(x1b, wpk, bpk, num_t, den_t);
  k_out    <<<NN / 32, 64, 0, stream>>>(num_t, den_t, x1b, wop, bo, g2, b2,
                                        flag, d_out);
}